// Round 1
// baseline (4795.250 us; speedup 1.0000x reference)
//
#include <hip/hip_runtime.h>
#include <hip/hip_bf16.h>
#include <math.h>

// ---------------- constants ----------------
namespace {
constexpr int Bc   = 2;
constexpr int Nn   = 2048;
constexpr int CACHE= 512;
constexpr int KVL  = 2560;      // CACHE + Nn
constexpr int DM   = 768;
constexpr int NH   = 12;
constexpr int HD   = 64;
constexpr int FFD  = 3072;
constexpr int RR   = Bc * Nn;   // 4096 rows
}
#define EPSF 1e-5f

// ---------------- helpers ----------------
__device__ __forceinline__ float geluf(float x) {
  float x3 = x * x * x;
  float t  = tanhf(0.7978845608028654f * (x + 0.044715f * x3));
  return 0.5f * x * (1.0f + t);
}
__device__ __forceinline__ float sigmoidf_(float x) {
  return 1.0f / (1.0f + __expf(-x));
}

// ---------------- rmsnorm: one block per row ----------------
__global__ __launch_bounds__(256) void k_rmsnorm(const float* __restrict__ in,
                                                 const float* __restrict__ w,
                                                 float* __restrict__ out, int D) {
  const int row = blockIdx.x;
  const float* x = in + (size_t)row * D;
  float* o = out + (size_t)row * D;
  float ss = 0.f;
  for (int i = threadIdx.x; i < D; i += 256) { float v = x[i]; ss = fmaf(v, v, ss); }
  __shared__ float red[5];
#pragma unroll
  for (int off = 32; off > 0; off >>= 1) ss += __shfl_down(ss, off, 64);
  if ((threadIdx.x & 63) == 0) red[threadIdx.x >> 6] = ss;
  __syncthreads();
  if (threadIdx.x == 0) red[4] = red[0] + red[1] + red[2] + red[3];
  __syncthreads();
  const float scale = rsqrtf(red[4] * (1.0f / (float)D) + EPSF);
  for (int i = threadIdx.x; i < D; i += 256) o[i] = x[i] * scale * w[i];
}

// ---------------- GEMM: C[M x Nc] = A[M x K] @ W[K x Nc] (+ epilogue) ------
// mode: 0 = +bias, 1 = gelu(+bias), 2 = 0.5*(+bias)+res, 3 = (+bias)+res
// 64x64 tile, 256 threads, 4x4 per thread. All dims divisible (M%64, Nc%64, K%16).
__global__ __launch_bounds__(256) void k_gemm(const float* __restrict__ A,
                                              const float* __restrict__ W,
                                              const float* __restrict__ bias,
                                              const float* __restrict__ res,
                                              float* __restrict__ C,
                                              int K, int Nc, int mode) {
  __shared__ float As[16][68];  // padded: float4-aligned rows, conflict-light
  __shared__ float Bs[16][64];
  const int tid = threadIdx.x;
  const int tx = tid & 15, ty = tid >> 4;
  const int rowBase = blockIdx.y * 64;
  const int colBase = blockIdx.x * 64;
  // A load: thread -> (row am, 4 k's); B load: thread -> (k bk, 4 cols)
  const int am = tid >> 2;
  const int ak = (tid & 3) * 4;
  const int bk = tid >> 4;
  const int bn = (tid & 15) * 4;
  float acc[4][4] = {};
  for (int k0 = 0; k0 < K; k0 += 16) {
    float4 av = *(const float4*)(A + (size_t)(rowBase + am) * K + (k0 + ak));
    float4 bv = *(const float4*)(W + (size_t)(k0 + bk) * Nc + (colBase + bn));
    As[ak + 0][am] = av.x; As[ak + 1][am] = av.y;
    As[ak + 2][am] = av.z; As[ak + 3][am] = av.w;
    *(float4*)&Bs[bk][bn] = bv;
    __syncthreads();
#pragma unroll
    for (int k = 0; k < 16; ++k) {
      const float4 a = *(const float4*)&As[k][ty * 4];
      const float4 b = *(const float4*)&Bs[k][tx * 4];
      acc[0][0] = fmaf(a.x, b.x, acc[0][0]); acc[0][1] = fmaf(a.x, b.y, acc[0][1]);
      acc[0][2] = fmaf(a.x, b.z, acc[0][2]); acc[0][3] = fmaf(a.x, b.w, acc[0][3]);
      acc[1][0] = fmaf(a.y, b.x, acc[1][0]); acc[1][1] = fmaf(a.y, b.y, acc[1][1]);
      acc[1][2] = fmaf(a.y, b.z, acc[1][2]); acc[1][3] = fmaf(a.y, b.w, acc[1][3]);
      acc[2][0] = fmaf(a.z, b.x, acc[2][0]); acc[2][1] = fmaf(a.z, b.y, acc[2][1]);
      acc[2][2] = fmaf(a.z, b.z, acc[2][2]); acc[2][3] = fmaf(a.z, b.w, acc[2][3]);
      acc[3][0] = fmaf(a.w, b.x, acc[3][0]); acc[3][1] = fmaf(a.w, b.y, acc[3][1]);
      acc[3][2] = fmaf(a.w, b.z, acc[3][2]); acc[3][3] = fmaf(a.w, b.w, acc[3][3]);
    }
    __syncthreads();
  }
  const int c = colBase + tx * 4;
  float bv0 = 0.f, bv1 = 0.f, bv2 = 0.f, bv3 = 0.f;
  if (bias) { bv0 = bias[c]; bv1 = bias[c + 1]; bv2 = bias[c + 2]; bv3 = bias[c + 3]; }
#pragma unroll
  for (int i = 0; i < 4; ++i) {
    const int r = rowBase + ty * 4 + i;
    float v0 = acc[i][0] + bv0, v1 = acc[i][1] + bv1;
    float v2 = acc[i][2] + bv2, v3 = acc[i][3] + bv3;
    if (mode == 1) {
      v0 = geluf(v0); v1 = geluf(v1); v2 = geluf(v2); v3 = geluf(v3);
    } else if (mode == 2) {
      const float* rp = res + (size_t)r * Nc + c;
      v0 = 0.5f * v0 + rp[0]; v1 = 0.5f * v1 + rp[1];
      v2 = 0.5f * v2 + rp[2]; v3 = 0.5f * v3 + rp[3];
    } else if (mode == 3) {
      const float* rp = res + (size_t)r * Nc + c;
      v0 += rp[0]; v1 += rp[1]; v2 += rp[2]; v3 += rp[3];
    }
    *(float4*)(C + (size_t)r * Nc + c) = make_float4(v0, v1, v2, v3);
  }
}

// ---------------- qkv split + q/k rmsnorm + kv emit ----------------
// one block per (b,n) row; 768 threads; wave w == head w (64 lanes == head_dim)
__global__ __launch_bounds__(768) void k_qkv_post(const float* __restrict__ qkv,
                                                  const float* __restrict__ qw,
                                                  const float* __restrict__ kw,
                                                  float* __restrict__ qout,
                                                  float* __restrict__ kvout) {
  const int row = blockIdx.x;             // b*Nn + n
  const int b = row >> 11;
  const int n = row & 2047;
  const int h = threadIdx.x >> 6;
  const int d = threadIdx.x & 63;
  const float* src = qkv + (size_t)row * (3 * DM) + h * 192 + d * 3;
  const float q = src[0], k = src[1], v = src[2];
  float sq = q * q, sk = k * k;
#pragma unroll
  for (int off = 32; off > 0; off >>= 1) {
    sq += __shfl_xor(sq, off, 64);
    sk += __shfl_xor(sk, off, 64);
  }
  const float qs = rsqrtf(sq * (1.0f / 64.0f) + EPSF);
  const float ks = rsqrtf(sk * (1.0f / 64.0f) + EPSF);
  const float qn = q * qs * qw[d];
  const float kn = k * ks * kw[d];
  qout[(size_t)row * DM + h * 64 + d] = qn;
  const size_t kvbase = ((size_t)b * KVL + (CACHE + n)) * (2 * DM) + h * 64 + d;
  kvout[kvbase] = kn;          // s = 0 (k)
  kvout[kvbase + DM] = v;      // s = 1 (v)
}

// ---------------- copy cached_kv into kv output rows 0..511 ----------------
__global__ __launch_bounds__(256) void k_copy_cache(const float* __restrict__ cached,
                                                    float* __restrict__ kvout) {
  const int e = blockIdx.x * 256 + threadIdx.x;   // float4 index, exact grid
  const int flat = e * 4;
  const int b = flat / (CACHE * 2 * DM);
  const int r = flat - b * (CACHE * 2 * DM);
  float4 v = *(const float4*)(cached + (size_t)b * (CACHE * 2 * DM) + r);
  *(float4*)(kvout + (size_t)b * (KVL * 2 * DM) + r) = v;
}

// ---------------- RoPE ----------------
// q: in-place on (B,N,H,64), pos = 512+n. 4 (b,n,h) rows per block.
__global__ __launch_bounds__(256) void k_rope_q(float* __restrict__ q) {
  const int hrow = blockIdx.x * 4 + (threadIdx.x >> 6);
  const int d = threadIdx.x & 63;
  const int n = (hrow / NH) & (Nn - 1);
  const float pos = (float)(CACHE + n);
  float* p = q + (size_t)hrow * 64;
  const float x = p[d];
  const int j = d & 31;
  const float inv = powf(10000.0f, -(float)j * (1.0f / 32.0f));
  float s, c;
  sincosf(pos * inv, &s, &c);
  const float other = __shfl_xor(x, 32, 64);
  const float rot = (d < 32) ? -other : other;
  p[d] = x * c + rot * s;
}

// k: read kv output (s=0 lanes), write krot (B,KV,H,64); pos = t
__global__ __launch_bounds__(256) void k_rope_k(const float* __restrict__ kvout,
                                                float* __restrict__ krot) {
  const int hrow = blockIdx.x * 4 + (threadIdx.x >> 6);  // (b,t,h)
  const int d = threadIdx.x & 63;
  const int b = hrow / (KVL * NH);
  const int rem = hrow - b * (KVL * NH);
  const int t = rem / NH;
  const int h = rem - t * NH;
  const float x = kvout[((size_t)b * KVL + t) * (2 * DM) + h * 64 + d];
  const int j = d & 31;
  const float inv = powf(10000.0f, -(float)j * (1.0f / 32.0f));
  float s, c;
  sincosf((float)t * inv, &s, &c);
  const float other = __shfl_xor(x, 32, 64);
  const float rot = (d < 32) ? -other : other;
  krot[(size_t)hrow * 64 + d] = x * c + rot * s;
}

// ---------------- flash attention ----------------
// grid = B*NH*(N/256); block 256. One query row per thread; K/V tiles (32x64) in LDS.
__global__ __launch_bounds__(256) void k_attn(const float* __restrict__ qrot,
                                              const float* __restrict__ krot,
                                              const float* __restrict__ kvout,
                                              float* __restrict__ out) {
  const int bh = blockIdx.x >> 3;
  const int qblk = blockIdx.x & 7;
  const int b = bh / NH, h = bh - b * NH;
  const int q = qblk * 256 + threadIdx.x;
  const float* qp = qrot + ((size_t)(b * Nn + q) * NH + h) * 64;
  float4 qv[16];
#pragma unroll
  for (int i = 0; i < 16; ++i) qv[i] = *(const float4*)(qp + i * 4);
  float4 acc[16];
#pragma unroll
  for (int i = 0; i < 16; ++i) acc[i] = make_float4(0.f, 0.f, 0.f, 0.f);
  float m = -1e30f, l = 0.f;
  __shared__ float ks[32][64];
  __shared__ float vs[32][64];
  for (int kv0 = 0; kv0 < KVL; kv0 += 32) {
    __syncthreads();
    int f = threadIdx.x;
#pragma unroll
    for (int it = 0; it < 2; ++it, f += 256) {
      const int r = f >> 4, d4 = (f & 15) * 4;
      *(float4*)&ks[r][d4] =
          *(const float4*)(krot + ((size_t)(b * KVL + kv0 + r) * NH + h) * 64 + d4);
      *(float4*)&vs[r][d4] =
          *(const float4*)(kvout + (size_t)(b * KVL + kv0 + r) * (2 * DM) + DM + h * 64 + d4);
    }
    __syncthreads();
    float s[32];
#pragma unroll
    for (int jj = 0; jj < 32; ++jj) {
      const float4* kr = (const float4*)&ks[jj][0];
      float dot = 0.f;
#pragma unroll
      for (int i = 0; i < 16; ++i) {
        const float4 kk = kr[i];
        dot = fmaf(qv[i].x, kk.x, dot); dot = fmaf(qv[i].y, kk.y, dot);
        dot = fmaf(qv[i].z, kk.z, dot); dot = fmaf(qv[i].w, kk.w, dot);
      }
      s[jj] = dot * 0.125f;
    }
    float tmax = s[0];
#pragma unroll
    for (int jj = 1; jj < 32; ++jj) tmax = fmaxf(tmax, s[jj]);
    const float mnew = fmaxf(m, tmax);
    const float corr = __expf(m - mnew);
    l *= corr;
#pragma unroll
    for (int i = 0; i < 16; ++i) {
      acc[i].x *= corr; acc[i].y *= corr; acc[i].z *= corr; acc[i].w *= corr;
    }
#pragma unroll
    for (int jj = 0; jj < 32; ++jj) {
      const float p = __expf(s[jj] - mnew);
      l += p;
      const float4* vr = (const float4*)&vs[jj][0];
#pragma unroll
      for (int i = 0; i < 16; ++i) {
        const float4 vv = vr[i];
        acc[i].x = fmaf(p, vv.x, acc[i].x); acc[i].y = fmaf(p, vv.y, acc[i].y);
        acc[i].z = fmaf(p, vv.z, acc[i].z); acc[i].w = fmaf(p, vv.w, acc[i].w);
      }
    }
    m = mnew;
  }
  const float inv_l = 1.0f / l;
  float* op = out + ((size_t)(b * Nn + q) * NH + h) * 64;
#pragma unroll
  for (int i = 0; i < 16; ++i) {
    *(float4*)(op + i * 4) = make_float4(acc[i].x * inv_l, acc[i].y * inv_l,
                                         acc[i].z * inv_l, acc[i].w * inv_l);
  }
}

// ---------------- conv-module elementwise ----------------
__global__ __launch_bounds__(256) void k_glu(const float* __restrict__ pw,
                                             float* __restrict__ out) {
  const int idx = blockIdx.x * 256 + threadIdx.x;
  const int row = idx / DM, c = idx - row * DM;
  const float a = pw[(size_t)row * (2 * DM) + c];
  const float g = pw[(size_t)row * (2 * DM) + DM + c];
  out[idx] = a * sigmoidf_(g);
}

__global__ __launch_bounds__(256) void k_dwconv(const float* __restrict__ glu,
                                                const float* __restrict__ w,
                                                const float* __restrict__ bsd,
                                                float* __restrict__ out) {
  const int idx = blockIdx.x * 256 + threadIdx.x;
  const int row = idx / DM, c = idx - row * DM;
  const int b = row >> 11, n = row & 2047;
  const float* g = glu + ((size_t)b * Nn) * DM + c;
  const float* wc = w + c * 31;
  float acc = bsd[c];
#pragma unroll
  for (int t = 0; t < 31; ++t) {
    const int nn = n + t - 15;
    if (nn >= 0 && nn < Nn) acc = fmaf(g[(size_t)nn * DM], wc[t], acc);
  }
  out[idx] = acc;
}

__global__ __launch_bounds__(256) void k_zero(float* __restrict__ p, int n) {
  const int i = blockIdx.x * 256 + threadIdx.x;
  if (i < n) p[i] = 0.f;
}

// per-block partial sums over 32 rows, atomics into stats[0:768]=sum, [768:1536]=sumsq
__global__ __launch_bounds__(256) void k_bn_stats(const float* __restrict__ x,
                                                  float* __restrict__ stats) {
  const int c0 = threadIdx.x;
  const int row0 = blockIdx.x * 32;
  float s0 = 0.f, s1 = 0.f, s2 = 0.f, q0 = 0.f, q1 = 0.f, q2 = 0.f;
  for (int r = 0; r < 32; ++r) {
    const float* p = x + (size_t)(row0 + r) * DM;
    const float v0 = p[c0], v1 = p[c0 + 256], v2 = p[c0 + 512];
    s0 += v0; q0 = fmaf(v0, v0, q0);
    s1 += v1; q1 = fmaf(v1, v1, q1);
    s2 += v2; q2 = fmaf(v2, v2, q2);
  }
  atomicAdd(&stats[c0], s0);        atomicAdd(&stats[DM + c0], q0);
  atomicAdd(&stats[c0 + 256], s1);  atomicAdd(&stats[DM + c0 + 256], q1);
  atomicAdd(&stats[c0 + 512], s2);  atomicAdd(&stats[DM + c0 + 512], q2);
}

__global__ __launch_bounds__(256) void k_bn_apply(float* __restrict__ x,
                                                  const float* __restrict__ stats,
                                                  const float* __restrict__ g,
                                                  const float* __restrict__ bb) {
  const int idx = blockIdx.x * 256 + threadIdx.x;
  const int c = idx % DM;
  const float mean = stats[c] * (1.0f / (float)RR);
  const float var = stats[DM + c] * (1.0f / (float)RR) - mean * mean;
  float y = (x[idx] - mean) * rsqrtf(var + EPSF) * g[c] + bb[c];
  x[idx] = y * sigmoidf_(y);
}

// ---------------- launch ----------------
extern "C" void kernel_launch(void* const* d_in, const int* in_sizes, int n_in,
                              void* d_out, int out_size, void* d_ws, size_t ws_size,
                              hipStream_t stream) {
  const float* x       = (const float*)d_in[0];
  const float* cached  = (const float*)d_in[4];
  const float* ff1_nw  = (const float*)d_in[5];
  const float* ff1_w1  = (const float*)d_in[6];
  const float* ff1_b1  = (const float*)d_in[7];
  const float* ff1_w2  = (const float*)d_in[8];
  const float* ff1_b2  = (const float*)d_in[9];
  const float* attn_nw = (const float*)d_in[10];
  const float* qkv_w   = (const float*)d_in[11];
  const float* out_w   = (const float*)d_in[12];
  const float* q_nw    = (const float*)d_in[13];
  const float* k_nw    = (const float*)d_in[14];
  const float* conv_nw = (const float*)d_in[15];
  const float* pw1_w   = (const float*)d_in[16];
  const float* pw1_b   = (const float*)d_in[17];
  const float* dw_w    = (const float*)d_in[18];
  const float* dw_b    = (const float*)d_in[19];
  const float* bn_g    = (const float*)d_in[20];
  const float* bn_b    = (const float*)d_in[21];
  const float* pw2_w   = (const float*)d_in[22];
  const float* pw2_b   = (const float*)d_in[23];
  const float* ff2_nw  = (const float*)d_in[24];
  const float* ff2_w1  = (const float*)d_in[25];
  const float* ff2_b1  = (const float*)d_in[26];
  const float* ff2_w2  = (const float*)d_in[27];
  const float* ff2_b2  = (const float*)d_in[28];
  const float* out_nw  = (const float*)d_in[29];

  float* out_x  = (float*)d_out;
  float* out_kv = out_x + (size_t)RR * DM;         // kv_to_cache region of d_out

  float* ws       = (float*)d_ws;
  float* buf_norm = ws;                            // RR*768
  float* buf_h    = buf_norm + (size_t)RR * DM;    // RR*3072 (ff hidden / pw1 out)
  float* buf_x1   = buf_h + (size_t)RR * FFD;      // RR*768
  float* buf_qkv  = buf_x1 + (size_t)RR * DM;      // RR*2304 (also y3)
  float* buf_q    = buf_qkv + (size_t)RR * 3 * DM; // RR*768 (q / glu / x4)
  float* buf_krot = buf_q + (size_t)RR * DM;       // B*KV*768
  float* buf_att  = buf_krot + (size_t)Bc * KVL * DM; // RR*768 (attn out / dw out)
  float* bn_stats = buf_att + (size_t)RR * DM;     // 1536

  const dim3 blk(256);
  // ---- FF1: x1 = 0.5*(gelu(rms(x)@w1+b1)@w2+b2) + x
  k_rmsnorm<<<RR, blk, 0, stream>>>(x, ff1_nw, buf_norm, DM);
  k_gemm<<<dim3(FFD / 64, RR / 64), blk, 0, stream>>>(buf_norm, ff1_w1, ff1_b1, nullptr, buf_h, DM, FFD, 1);
  k_gemm<<<dim3(DM / 64, RR / 64), blk, 0, stream>>>(buf_h, ff1_w2, ff1_b2, x, buf_x1, FFD, DM, 2);
  // ---- Attention
  k_rmsnorm<<<RR, blk, 0, stream>>>(buf_x1, attn_nw, buf_norm, DM);
  k_gemm<<<dim3(3 * DM / 64, RR / 64), blk, 0, stream>>>(buf_norm, qkv_w, nullptr, nullptr, buf_qkv, DM, 3 * DM, 0);
  k_qkv_post<<<RR, 768, 0, stream>>>(buf_qkv, q_nw, k_nw, buf_q, out_kv);
  k_copy_cache<<<(Bc * CACHE * 2 * DM) / 4 / 256, blk, 0, stream>>>(cached, out_kv);
  k_rope_q<<<RR * NH / 4, blk, 0, stream>>>(buf_q);
  k_rope_k<<<Bc * KVL * NH / 4, blk, 0, stream>>>(out_kv, buf_krot);
  k_attn<<<Bc * NH * (Nn / 256), blk, 0, stream>>>(buf_q, buf_krot, out_kv, buf_att);
  k_gemm<<<dim3(DM / 64, RR / 64), blk, 0, stream>>>(buf_att, out_w, nullptr, buf_x1, buf_norm, DM, DM, 3); // x2 -> buf_norm
  // ---- Conv module (no residual)
  k_rmsnorm<<<RR, blk, 0, stream>>>(buf_norm, conv_nw, buf_qkv, DM);  // y3 -> buf_qkv
  k_gemm<<<dim3(2 * DM / 64, RR / 64), blk, 0, stream>>>(buf_qkv, pw1_w, pw1_b, nullptr, buf_h, DM, 2 * DM, 0);
  k_glu<<<RR * DM / 256, blk, 0, stream>>>(buf_h, buf_q);
  k_dwconv<<<RR * DM / 256, blk, 0, stream>>>(buf_q, dw_w, dw_b, buf_att);
  k_zero<<<6, blk, 0, stream>>>(bn_stats, 2 * DM);
  k_bn_stats<<<RR / 32, blk, 0, stream>>>(buf_att, bn_stats);
  k_bn_apply<<<RR * DM / 256, blk, 0, stream>>>(buf_att, bn_stats, bn_g, bn_b);
  k_gemm<<<dim3(DM / 64, RR / 64), blk, 0, stream>>>(buf_att, pw2_w, pw2_b, nullptr, buf_x1, DM, DM, 0);  // x3 -> buf_x1
  // ---- FF2
  k_rmsnorm<<<RR, blk, 0, stream>>>(buf_x1, ff2_nw, buf_norm, DM);
  k_gemm<<<dim3(FFD / 64, RR / 64), blk, 0, stream>>>(buf_norm, ff2_w1, ff2_b1, nullptr, buf_h, DM, FFD, 1);
  k_gemm<<<dim3(DM / 64, RR / 64), blk, 0, stream>>>(buf_h, ff2_w2, ff2_b2, buf_x1, buf_q, FFD, DM, 2);   // x4 -> buf_q
  // ---- final norm -> output 0
  k_rmsnorm<<<RR, blk, 0, stream>>>(buf_q, out_nw, out_x, DM);
}

// Round 2
// 2272.025 us; speedup vs baseline: 2.1106x; 2.1106x over previous
//
#include <hip/hip_runtime.h>
#include <hip/hip_bf16.h>
#include <math.h>

// ---------------- constants ----------------
namespace {
constexpr int Bc   = 2;
constexpr int Nn   = 2048;
constexpr int CACHE= 512;
constexpr int KVL  = 2560;      // CACHE + Nn
constexpr int DM   = 768;
constexpr int NH   = 12;
constexpr int HD   = 64;
constexpr int FFD  = 3072;
constexpr int RR   = Bc * Nn;   // 4096 rows
}
#define EPSF 1e-5f

typedef unsigned short u16;
typedef __bf16 bf16x8 __attribute__((ext_vector_type(8)));
typedef float  f32x4  __attribute__((ext_vector_type(4)));
typedef u16    u16x8  __attribute__((ext_vector_type(8)));

// ---------------- helpers ----------------
__device__ __forceinline__ float geluf(float x) {
  float x3 = x * x * x;
  float t  = tanhf(0.7978845608028654f * (x + 0.044715f * x3));
  return 0.5f * x * (1.0f + t);
}
__device__ __forceinline__ float sigmoidf_(float x) {
  return 1.0f / (1.0f + __expf(-x));
}
__device__ __forceinline__ u16 f2bf(float x) {
  union { float f; unsigned u; } v; v.f = x;
  unsigned r = (v.u + 0x7fffu + ((v.u >> 16) & 1u)) >> 16;
  return (u16)r;
}

// ---------------- rmsnorm: one block per row ----------------
__global__ __launch_bounds__(256) void k_rmsnorm(const float* __restrict__ in,
                                                 const float* __restrict__ w,
                                                 float* __restrict__ out, int D) {
  const int row = blockIdx.x;
  const float* x = in + (size_t)row * D;
  float* o = out + (size_t)row * D;
  float ss = 0.f;
  for (int i = threadIdx.x; i < D; i += 256) { float v = x[i]; ss = fmaf(v, v, ss); }
  __shared__ float red[5];
#pragma unroll
  for (int off = 32; off > 0; off >>= 1) ss += __shfl_down(ss, off, 64);
  if ((threadIdx.x & 63) == 0) red[threadIdx.x >> 6] = ss;
  __syncthreads();
  if (threadIdx.x == 0) red[4] = red[0] + red[1] + red[2] + red[3];
  __syncthreads();
  const float scale = rsqrtf(red[4] * (1.0f / (float)D) + EPSF);
  for (int i = threadIdx.x; i < D; i += 256) o[i] = x[i] * scale * w[i];
}

// ---------------- GEMM: C[M x Nc] = A[M x K] @ W[K x Nc] (+ epilogue) ------
// mode: 0 = +bias, 1 = gelu(+bias), 2 = 0.5*(+bias)+res, 3 = (+bias)+res
__global__ __launch_bounds__(256) void k_gemm(const float* __restrict__ A,
                                              const float* __restrict__ W,
                                              const float* __restrict__ bias,
                                              const float* __restrict__ res,
                                              float* __restrict__ C,
                                              int K, int Nc, int mode) {
  __shared__ float As[16][68];
  __shared__ float Bs[16][64];
  const int tid = threadIdx.x;
  const int tx = tid & 15, ty = tid >> 4;
  const int rowBase = blockIdx.y * 64;
  const int colBase = blockIdx.x * 64;
  const int am = tid >> 2;
  const int ak = (tid & 3) * 4;
  const int bk = tid >> 4;
  const int bn = (tid & 15) * 4;
  float acc[4][4] = {};
  for (int k0 = 0; k0 < K; k0 += 16) {
    float4 av = *(const float4*)(A + (size_t)(rowBase + am) * K + (k0 + ak));
    float4 bv = *(const float4*)(W + (size_t)(k0 + bk) * Nc + (colBase + bn));
    As[ak + 0][am] = av.x; As[ak + 1][am] = av.y;
    As[ak + 2][am] = av.z; As[ak + 3][am] = av.w;
    *(float4*)&Bs[bk][bn] = bv;
    __syncthreads();
#pragma unroll
    for (int k = 0; k < 16; ++k) {
      const float4 a = *(const float4*)&As[k][ty * 4];
      const float4 b = *(const float4*)&Bs[k][tx * 4];
      acc[0][0] = fmaf(a.x, b.x, acc[0][0]); acc[0][1] = fmaf(a.x, b.y, acc[0][1]);
      acc[0][2] = fmaf(a.x, b.z, acc[0][2]); acc[0][3] = fmaf(a.x, b.w, acc[0][3]);
      acc[1][0] = fmaf(a.y, b.x, acc[1][0]); acc[1][1] = fmaf(a.y, b.y, acc[1][1]);
      acc[1][2] = fmaf(a.y, b.z, acc[1][2]); acc[1][3] = fmaf(a.y, b.w, acc[1][3]);
      acc[2][0] = fmaf(a.z, b.x, acc[2][0]); acc[2][1] = fmaf(a.z, b.y, acc[2][1]);
      acc[2][2] = fmaf(a.z, b.z, acc[2][2]); acc[2][3] = fmaf(a.z, b.w, acc[2][3]);
      acc[3][0] = fmaf(a.w, b.x, acc[3][0]); acc[3][1] = fmaf(a.w, b.y, acc[3][1]);
      acc[3][2] = fmaf(a.w, b.z, acc[3][2]); acc[3][3] = fmaf(a.w, b.w, acc[3][3]);
    }
    __syncthreads();
  }
  const int c = colBase + tx * 4;
  float bv0 = 0.f, bv1 = 0.f, bv2 = 0.f, bv3 = 0.f;
  if (bias) { bv0 = bias[c]; bv1 = bias[c + 1]; bv2 = bias[c + 2]; bv3 = bias[c + 3]; }
#pragma unroll
  for (int i = 0; i < 4; ++i) {
    const int r = rowBase + ty * 4 + i;
    float v0 = acc[i][0] + bv0, v1 = acc[i][1] + bv1;
    float v2 = acc[i][2] + bv2, v3 = acc[i][3] + bv3;
    if (mode == 1) {
      v0 = geluf(v0); v1 = geluf(v1); v2 = geluf(v2); v3 = geluf(v3);
    } else if (mode == 2) {
      const float* rp = res + (size_t)r * Nc + c;
      v0 = 0.5f * v0 + rp[0]; v1 = 0.5f * v1 + rp[1];
      v2 = 0.5f * v2 + rp[2]; v3 = 0.5f * v3 + rp[3];
    } else if (mode == 3) {
      const float* rp = res + (size_t)r * Nc + c;
      v0 += rp[0]; v1 += rp[1]; v2 += rp[2]; v3 += rp[3];
    }
    *(float4*)(C + (size_t)r * Nc + c) = make_float4(v0, v1, v2, v3);
  }
}

// ---------------- qkv split + q/k rmsnorm + kv emit ----------------
__global__ __launch_bounds__(768) void k_qkv_post(const float* __restrict__ qkv,
                                                  const float* __restrict__ qw,
                                                  const float* __restrict__ kw,
                                                  float* __restrict__ qout,
                                                  float* __restrict__ kvout) {
  const int row = blockIdx.x;             // b*Nn + n
  const int b = row >> 11;
  const int n = row & 2047;
  const int h = threadIdx.x >> 6;
  const int d = threadIdx.x & 63;
  const float* src = qkv + (size_t)row * (3 * DM) + h * 192 + d * 3;
  const float q = src[0], k = src[1], v = src[2];
  float sq = q * q, sk = k * k;
#pragma unroll
  for (int off = 32; off > 0; off >>= 1) {
    sq += __shfl_xor(sq, off, 64);
    sk += __shfl_xor(sk, off, 64);
  }
  const float qs = rsqrtf(sq * (1.0f / 64.0f) + EPSF);
  const float ks = rsqrtf(sk * (1.0f / 64.0f) + EPSF);
  const float qn = q * qs * qw[d];
  const float kn = k * ks * kw[d];
  qout[(size_t)row * DM + h * 64 + d] = qn;
  const size_t kvbase = ((size_t)b * KVL + (CACHE + n)) * (2 * DM) + h * 64 + d;
  kvout[kvbase] = kn;          // s = 0 (k)
  kvout[kvbase + DM] = v;      // s = 1 (v)
}

// ---------------- copy cached_kv into kv output rows 0..511 ----------------
__global__ __launch_bounds__(256) void k_copy_cache(const float* __restrict__ cached,
                                                    float* __restrict__ kvout) {
  const int e = blockIdx.x * 256 + threadIdx.x;
  const int flat = e * 4;
  const int b = flat / (CACHE * 2 * DM);
  const int r = flat - b * (CACHE * 2 * DM);
  float4 v = *(const float4*)(cached + (size_t)b * (CACHE * 2 * DM) + r);
  *(float4*)(kvout + (size_t)b * (KVL * 2 * DM) + r) = v;
}

// ---------------- RoPE (emit bf16) ----------------
// q: read fp32 normed q (B,N,H,64), pos = 512+n -> qbf bf16
__global__ __launch_bounds__(256) void k_rope_q(const float* __restrict__ q,
                                                u16* __restrict__ qbf) {
  const int hrow = blockIdx.x * 4 + (threadIdx.x >> 6);
  const int d = threadIdx.x & 63;
  const int n = (hrow / NH) & (Nn - 1);
  const float pos = (float)(CACHE + n);
  const float x = q[(size_t)hrow * 64 + d];
  const int j = d & 31;
  const float inv = powf(10000.0f, -(float)j * (1.0f / 32.0f));
  float s, c;
  sincosf(pos * inv, &s, &c);
  const float other = __shfl_xor(x, 32, 64);
  const float rot = (d < 32) ? -other : other;
  qbf[(size_t)hrow * 64 + d] = f2bf(x * c + rot * s);
}

// k: read kv output (s=0 lanes), write krotbf bf16 (B,KVL,H,64); pos = t
__global__ __launch_bounds__(256) void k_rope_k(const float* __restrict__ kvout,
                                                u16* __restrict__ krotbf) {
  const int hrow = blockIdx.x * 4 + (threadIdx.x >> 6);  // (b,t,h)
  const int d = threadIdx.x & 63;
  const int b = hrow / (KVL * NH);
  const int rem = hrow - b * (KVL * NH);
  const int t = rem / NH;
  const int h = rem - t * NH;
  const float x = kvout[((size_t)b * KVL + t) * (2 * DM) + h * 64 + d];
  const int j = d & 31;
  const float inv = powf(10000.0f, -(float)j * (1.0f / 32.0f));
  float s, c;
  sincosf((float)t * inv, &s, &c);
  const float other = __shfl_xor(x, 32, 64);
  const float rot = (d < 32) ? -other : other;
  krotbf[(size_t)hrow * 64 + d] = f2bf(x * c + rot * s);
}

// ---------------- V transpose: (B,KVL,H,64) f32 -> vtbf (B,H,64,KVL) bf16 ----
__global__ __launch_bounds__(256) void k_vt(const float* __restrict__ kvout,
                                            u16* __restrict__ vtbf) {
  __shared__ u16 T[64][72];
  const int bh = blockIdx.x / 40;       // KVL/64 = 40 tiles per (b,h)
  const int tb = blockIdx.x % 40;
  const int b = bh / NH, h = bh % NH;
  const int t0 = tb * 64;
  {
    const int tloc = threadIdx.x >> 2;        // key in tile
    const int dg = (threadIdx.x & 3) * 16;    // dim group
    const float* src = kvout + ((size_t)b * KVL + t0 + tloc) * (2 * DM) + DM + h * 64 + dg;
    float4 v0 = *(const float4*)(src);
    float4 v1 = *(const float4*)(src + 4);
    float4 v2 = *(const float4*)(src + 8);
    float4 v3 = *(const float4*)(src + 12);
    T[dg + 0][tloc] = f2bf(v0.x);  T[dg + 1][tloc] = f2bf(v0.y);
    T[dg + 2][tloc] = f2bf(v0.z);  T[dg + 3][tloc] = f2bf(v0.w);
    T[dg + 4][tloc] = f2bf(v1.x);  T[dg + 5][tloc] = f2bf(v1.y);
    T[dg + 6][tloc] = f2bf(v1.z);  T[dg + 7][tloc] = f2bf(v1.w);
    T[dg + 8][tloc] = f2bf(v2.x);  T[dg + 9][tloc] = f2bf(v2.y);
    T[dg + 10][tloc] = f2bf(v2.z); T[dg + 11][tloc] = f2bf(v2.w);
    T[dg + 12][tloc] = f2bf(v3.x); T[dg + 13][tloc] = f2bf(v3.y);
    T[dg + 14][tloc] = f2bf(v3.z); T[dg + 15][tloc] = f2bf(v3.w);
  }
  __syncthreads();
  const int d = threadIdx.x >> 2;
  const int kg = (threadIdx.x & 3) * 16;
  u16x8 a = *(const u16x8*)&T[d][kg];
  u16x8 b8 = *(const u16x8*)&T[d][kg + 8];
  u16* dst = vtbf + ((size_t)(b * NH + h) * 64 + d) * KVL + t0 + kg;
  *(u16x8*)dst = a;
  *(u16x8*)(dst + 8) = b8;
}

// ---------------- MFMA flash attention ----------------
// block = 256 (4 waves); each wave owns 16 queries; block owns 64.
// grid = B*NH*(Nn/64) = 768. KV tiles of 64 keys staged in LDS.
__global__ __launch_bounds__(256) void k_attn_mfma(const u16* __restrict__ qbf,
                                                   const u16* __restrict__ krotbf,
                                                   const u16* __restrict__ vtbf,
                                                   float* __restrict__ out) {
  __shared__ u16 Ks[64][72];      // [key][dim]
  __shared__ u16 Vs[64][72];      // [dim][key]  (transposed V)
  __shared__ u16 Ps[4][16][72];   // per-wave P: [query][key]
  const int lane = threadIdx.x & 63;
  const int wid  = threadIdx.x >> 6;
  const int qblk = blockIdx.x & 31;
  const int bh   = blockIdx.x >> 5;
  const int b = bh / NH, h = bh % NH;
  const int q0 = qblk * 64 + wid * 16;
  const int l15 = lane & 15;
  const int quad = lane >> 4;

  // Q fragments (A-layout: lane holds Q[l15][quad*8 + j])
  const u16* qptr = qbf + ((size_t)(b * Nn + q0 + l15) * NH + h) * 64 + quad * 8;
  const bf16x8 aQ0 = *(const bf16x8*)qptr;
  const bf16x8 aQ1 = *(const bf16x8*)(qptr + 32);

  f32x4 O[4] = {};                 // [out-dim tile][reg]; row=quad*4+reg, col=ot*16+l15
  float m_[4] = {-1e30f, -1e30f, -1e30f, -1e30f};
  float l_[4] = {};

  for (int kv0 = 0; kv0 < KVL; kv0 += 64) {
    __syncthreads();
    // stage K (64 keys x 64 dims) and Vt (64 dims x 64 keys): 512 u16x8 chunks each
    {
      int c = threadIdx.x;
#pragma unroll
      for (int it = 0; it < 2; ++it, c += 256) {
        const int r = c >> 3, part = (c & 7) * 8;
        *(u16x8*)&Ks[r][part] =
            *(const u16x8*)(krotbf + ((size_t)(b * KVL + kv0 + r) * NH + h) * 64 + part);
        *(u16x8*)&Vs[r][part] =
            *(const u16x8*)(vtbf + ((size_t)(b * NH + h) * 64 + r) * KVL + kv0 + part);
      }
    }
    __syncthreads();

    // S = Q K^T for 4 key tiles of 16
    float s[4][4];
#pragma unroll
    for (int nt = 0; nt < 4; ++nt) {
      const bf16x8 bK0 = *(const bf16x8*)&Ks[nt * 16 + l15][quad * 8];
      const bf16x8 bK1 = *(const bf16x8*)&Ks[nt * 16 + l15][32 + quad * 8];
      f32x4 c = {};
      c = __builtin_amdgcn_mfma_f32_16x16x32_bf16(aQ0, bK0, c, 0, 0, 0);
      c = __builtin_amdgcn_mfma_f32_16x16x32_bf16(aQ1, bK1, c, 0, 0, 0);
#pragma unroll
      for (int r = 0; r < 4; ++r) s[nt][r] = c[r] * 0.125f;
    }

    // online softmax per query row (row = quad*4 + r)
#pragma unroll
    for (int r = 0; r < 4; ++r) {
      float t = fmaxf(fmaxf(s[0][r], s[1][r]), fmaxf(s[2][r], s[3][r]));
      t = fmaxf(t, __shfl_xor(t, 1, 64));
      t = fmaxf(t, __shfl_xor(t, 2, 64));
      t = fmaxf(t, __shfl_xor(t, 4, 64));
      t = fmaxf(t, __shfl_xor(t, 8, 64));
      const float mnew = fmaxf(m_[r], t);
      const float alpha = __expf(m_[r] - mnew);
      float rs = 0.f;
#pragma unroll
      for (int nt = 0; nt < 4; ++nt) { s[nt][r] = __expf(s[nt][r] - mnew); rs += s[nt][r]; }
      rs += __shfl_xor(rs, 1, 64);
      rs += __shfl_xor(rs, 2, 64);
      rs += __shfl_xor(rs, 4, 64);
      rs += __shfl_xor(rs, 8, 64);
      l_[r] = alpha * l_[r] + rs;
      m_[r] = mnew;
#pragma unroll
      for (int ot = 0; ot < 4; ++ot) O[ot][r] *= alpha;
    }

    // write P to per-wave LDS (C-layout -> row-major [query][key])
#pragma unroll
    for (int nt = 0; nt < 4; ++nt)
#pragma unroll
      for (int r = 0; r < 4; ++r)
        Ps[wid][quad * 4 + r][nt * 16 + l15] = f2bf(s[nt][r]);
    __syncthreads();

    // O += P V   (A-frag from Ps, B-frag from Vs)
#pragma unroll
    for (int kt = 0; kt < 2; ++kt) {
      const bf16x8 aP = *(const bf16x8*)&Ps[wid][l15][kt * 32 + quad * 8];
#pragma unroll
      for (int ot = 0; ot < 4; ++ot) {
        const bf16x8 bV = *(const bf16x8*)&Vs[ot * 16 + l15][kt * 32 + quad * 8];
        O[ot] = __builtin_amdgcn_mfma_f32_16x16x32_bf16(aP, bV, O[ot], 0, 0, 0);
      }
    }
  }

  // epilogue: normalize and store (B,N, H*64)
#pragma unroll
  for (int r = 0; r < 4; ++r) {
    const float inv = 1.0f / l_[r];
    const int q = q0 + quad * 4 + r;
    float* op = out + ((size_t)(b * Nn + q)) * DM + h * 64;
#pragma unroll
    for (int ot = 0; ot < 4; ++ot) op[ot * 16 + l15] = O[ot][r] * inv;
  }
}

// ---------------- conv-module elementwise ----------------
__global__ __launch_bounds__(256) void k_glu(const float* __restrict__ pw,
                                             float* __restrict__ out) {
  const int idx = blockIdx.x * 256 + threadIdx.x;
  const int row = idx / DM, c = idx - row * DM;
  const float a = pw[(size_t)row * (2 * DM) + c];
  const float g = pw[(size_t)row * (2 * DM) + DM + c];
  out[idx] = a * sigmoidf_(g);
}

__global__ __launch_bounds__(256) void k_dwconv(const float* __restrict__ glu,
                                                const float* __restrict__ w,
                                                const float* __restrict__ bsd,
                                                float* __restrict__ out) {
  const int idx = blockIdx.x * 256 + threadIdx.x;
  const int row = idx / DM, c = idx - row * DM;
  const int b = row >> 11, n = row & 2047;
  const float* g = glu + ((size_t)b * Nn) * DM + c;
  const float* wc = w + c * 31;
  float acc = bsd[c];
#pragma unroll
  for (int t = 0; t < 31; ++t) {
    const int nn = n + t - 15;
    if (nn >= 0 && nn < Nn) acc = fmaf(g[(size_t)nn * DM], wc[t], acc);
  }
  out[idx] = acc;
}

__global__ __launch_bounds__(256) void k_zero(float* __restrict__ p, int n) {
  const int i = blockIdx.x * 256 + threadIdx.x;
  if (i < n) p[i] = 0.f;
}

__global__ __launch_bounds__(256) void k_bn_stats(const float* __restrict__ x,
                                                  float* __restrict__ stats) {
  const int c0 = threadIdx.x;
  const int row0 = blockIdx.x * 32;
  float s0 = 0.f, s1 = 0.f, s2 = 0.f, q0 = 0.f, q1 = 0.f, q2 = 0.f;
  for (int r = 0; r < 32; ++r) {
    const float* p = x + (size_t)(row0 + r) * DM;
    const float v0 = p[c0], v1 = p[c0 + 256], v2 = p[c0 + 512];
    s0 += v0; q0 = fmaf(v0, v0, q0);
    s1 += v1; q1 = fmaf(v1, v1, q1);
    s2 += v2; q2 = fmaf(v2, v2, q2);
  }
  atomicAdd(&stats[c0], s0);        atomicAdd(&stats[DM + c0], q0);
  atomicAdd(&stats[c0 + 256], s1);  atomicAdd(&stats[DM + c0 + 256], q1);
  atomicAdd(&stats[c0 + 512], s2);  atomicAdd(&stats[DM + c0 + 512], q2);
}

__global__ __launch_bounds__(256) void k_bn_apply(float* __restrict__ x,
                                                  const float* __restrict__ stats,
                                                  const float* __restrict__ g,
                                                  const float* __restrict__ bb) {
  const int idx = blockIdx.x * 256 + threadIdx.x;
  const int c = idx % DM;
  const float mean = stats[c] * (1.0f / (float)RR);
  const float var = stats[DM + c] * (1.0f / (float)RR) - mean * mean;
  float y = (x[idx] - mean) * rsqrtf(var + EPSF) * g[c] + bb[c];
  x[idx] = y * sigmoidf_(y);
}

// ---------------- launch ----------------
extern "C" void kernel_launch(void* const* d_in, const int* in_sizes, int n_in,
                              void* d_out, int out_size, void* d_ws, size_t ws_size,
                              hipStream_t stream) {
  const float* x       = (const float*)d_in[0];
  const float* cached  = (const float*)d_in[4];
  const float* ff1_nw  = (const float*)d_in[5];
  const float* ff1_w1  = (const float*)d_in[6];
  const float* ff1_b1  = (const float*)d_in[7];
  const float* ff1_w2  = (const float*)d_in[8];
  const float* ff1_b2  = (const float*)d_in[9];
  const float* attn_nw = (const float*)d_in[10];
  const float* qkv_w   = (const float*)d_in[11];
  const float* out_w   = (const float*)d_in[12];
  const float* q_nw    = (const float*)d_in[13];
  const float* k_nw    = (const float*)d_in[14];
  const float* conv_nw = (const float*)d_in[15];
  const float* pw1_w   = (const float*)d_in[16];
  const float* pw1_b   = (const float*)d_in[17];
  const float* dw_w    = (const float*)d_in[18];
  const float* dw_b    = (const float*)d_in[19];
  const float* bn_g    = (const float*)d_in[20];
  const float* bn_b    = (const float*)d_in[21];
  const float* pw2_w   = (const float*)d_in[22];
  const float* pw2_b   = (const float*)d_in[23];
  const float* ff2_nw  = (const float*)d_in[24];
  const float* ff2_w1  = (const float*)d_in[25];
  const float* ff2_b1  = (const float*)d_in[26];
  const float* ff2_w2  = (const float*)d_in[27];
  const float* ff2_b2  = (const float*)d_in[28];
  const float* out_nw  = (const float*)d_in[29];

  float* out_x  = (float*)d_out;
  float* out_kv = out_x + (size_t)RR * DM;

  float* ws       = (float*)d_ws;
  float* buf_norm = ws;                              // RR*768
  float* buf_h    = buf_norm + (size_t)RR * DM;      // RR*3072
  float* buf_x1   = buf_h + (size_t)RR * FFD;        // RR*768
  float* buf_qkv  = buf_x1 + (size_t)RR * DM;        // RR*2304
  float* buf_q    = buf_qkv + (size_t)RR * 3 * DM;   // RR*768 (normed q / glu / x4)
  float* buf_att  = buf_q + (size_t)RR * DM;         // RR*768
  float* bn_stats = buf_att + (size_t)RR * DM;       // 1536
  u16* qbf    = (u16*)(bn_stats + 2 * DM);           // RR*768 bf16
  u16* krotbf = qbf + (size_t)RR * DM;               // B*KVL*768 bf16
  u16* vtbf   = krotbf + (size_t)Bc * KVL * DM;      // B*H*64*KVL bf16

  const dim3 blk(256);
  // ---- FF1
  k_rmsnorm<<<RR, blk, 0, stream>>>(x, ff1_nw, buf_norm, DM);
  k_gemm<<<dim3(FFD / 64, RR / 64), blk, 0, stream>>>(buf_norm, ff1_w1, ff1_b1, nullptr, buf_h, DM, FFD, 1);
  k_gemm<<<dim3(DM / 64, RR / 64), blk, 0, stream>>>(buf_h, ff1_w2, ff1_b2, x, buf_x1, FFD, DM, 2);
  // ---- Attention
  k_rmsnorm<<<RR, blk, 0, stream>>>(buf_x1, attn_nw, buf_norm, DM);
  k_gemm<<<dim3(3 * DM / 64, RR / 64), blk, 0, stream>>>(buf_norm, qkv_w, nullptr, nullptr, buf_qkv, DM, 3 * DM, 0);
  k_qkv_post<<<RR, 768, 0, stream>>>(buf_qkv, q_nw, k_nw, buf_q, out_kv);
  k_copy_cache<<<(Bc * CACHE * 2 * DM) / 4 / 256, blk, 0, stream>>>(cached, out_kv);
  k_rope_q<<<RR * NH / 4, blk, 0, stream>>>(buf_q, qbf);
  k_rope_k<<<Bc * KVL * NH / 4, blk, 0, stream>>>(out_kv, krotbf);
  k_vt<<<Bc * NH * (KVL / 64), blk, 0, stream>>>(out_kv, vtbf);
  k_attn_mfma<<<Bc * NH * (Nn / 64), blk, 0, stream>>>(qbf, krotbf, vtbf, buf_att);
  k_gemm<<<dim3(DM / 64, RR / 64), blk, 0, stream>>>(buf_att, out_w, nullptr, buf_x1, buf_norm, DM, DM, 3);
  // ---- Conv module
  k_rmsnorm<<<RR, blk, 0, stream>>>(buf_norm, conv_nw, buf_qkv, DM);
  k_gemm<<<dim3(2 * DM / 64, RR / 64), blk, 0, stream>>>(buf_qkv, pw1_w, pw1_b, nullptr, buf_h, DM, 2 * DM, 0);
  k_glu<<<RR * DM / 256, blk, 0, stream>>>(buf_h, buf_q);
  k_dwconv<<<RR * DM / 256, blk, 0, stream>>>(buf_q, dw_w, dw_b, buf_att);
  k_zero<<<6, blk, 0, stream>>>(bn_stats, 2 * DM);
  k_bn_stats<<<RR / 32, blk, 0, stream>>>(buf_att, bn_stats);
  k_bn_apply<<<RR * DM / 256, blk, 0, stream>>>(buf_att, bn_stats, bn_g, bn_b);
  k_gemm<<<dim3(DM / 64, RR / 64), blk, 0, stream>>>(buf_att, pw2_w, pw2_b, nullptr, buf_x1, DM, DM, 0);
  // ---- FF2
  k_rmsnorm<<<RR, blk, 0, stream>>>(buf_x1, ff2_nw, buf_norm, DM);
  k_gemm<<<dim3(FFD / 64, RR / 64), blk, 0, stream>>>(buf_norm, ff2_w1, ff2_b1, nullptr, buf_h, DM, FFD, 1);
  k_gemm<<<dim3(DM / 64, RR / 64), blk, 0, stream>>>(buf_h, ff2_w2, ff2_b2, buf_x1, buf_q, FFD, DM, 2);
  // ---- final norm
  k_rmsnorm<<<RR, blk, 0, stream>>>(buf_q, out_nw, out_x, DM);
}

// Round 3
// 743.548 us; speedup vs baseline: 6.4491x; 3.0557x over previous
//
#include <hip/hip_runtime.h>
#include <hip/hip_bf16.h>
#include <math.h>

// ---------------- constants ----------------
namespace {
constexpr int Bc   = 2;
constexpr int Nn   = 2048;
constexpr int CACHE= 512;
constexpr int KVL  = 2560;      // CACHE + Nn
constexpr int DM   = 768;
constexpr int NH   = 12;
constexpr int HD   = 64;
constexpr int FFD  = 3072;
constexpr int RR   = Bc * Nn;   // 4096 rows
}
#define EPSF 1e-5f

typedef unsigned short u16;
typedef __bf16 bf16x8 __attribute__((ext_vector_type(8)));
typedef float  f32x4  __attribute__((ext_vector_type(4)));
typedef u16    u16x8  __attribute__((ext_vector_type(8)));
typedef u16    u16x4  __attribute__((ext_vector_type(4)));

#define GPTR(p) ((const __attribute__((address_space(1))) void*)(p))
#define LPTR(p) ((__attribute__((address_space(3))) void*)(p))

// ---------------- helpers ----------------
__device__ __forceinline__ float geluf(float x) {
  float x3 = x * x * x;
  float t  = tanhf(0.7978845608028654f * (x + 0.044715f * x3));
  return 0.5f * x * (1.0f + t);
}
__device__ __forceinline__ float sigmoidf_(float x) {
  return 1.0f / (1.0f + __expf(-x));
}
__device__ __forceinline__ u16 f2bf(float x) {
  union { float f; unsigned u; } v; v.f = x;
  unsigned r = (v.u + 0x7fffu + ((v.u >> 16) & 1u)) >> 16;
  return (u16)r;
}
__device__ __forceinline__ float bf2f(u16 u) {
  union { unsigned u; float f; } v; v.u = ((unsigned)u) << 16;
  return v.f;
}

// ---------------- rmsnorm: one block per row; bf16 or fp32 out ----------------
template<bool BF>
__global__ __launch_bounds__(256) void k_rmsnorm2(const float* __restrict__ in,
                                                  const float* __restrict__ w,
                                                  void* __restrict__ outv, int D) {
  const int row = blockIdx.x;
  const float* x = in + (size_t)row * D;
  float ss = 0.f;
  for (int i = threadIdx.x; i < D; i += 256) { float v = x[i]; ss = fmaf(v, v, ss); }
  __shared__ float red[5];
#pragma unroll
  for (int off = 32; off > 0; off >>= 1) ss += __shfl_down(ss, off, 64);
  if ((threadIdx.x & 63) == 0) red[threadIdx.x >> 6] = ss;
  __syncthreads();
  if (threadIdx.x == 0) red[4] = red[0] + red[1] + red[2] + red[3];
  __syncthreads();
  const float scale = rsqrtf(red[4] * (1.0f / (float)D) + EPSF);
  for (int i = threadIdx.x; i < D; i += 256) {
    const float v = x[i] * scale * w[i];
    if (BF) ((u16*)outv)[(size_t)row * D + i] = f2bf(v);
    else    ((float*)outv)[(size_t)row * D + i] = v;
  }
}

// ---------------- weight prep: W (K x N) f32 -> Wt (N x K) bf16 ----------------
__global__ __launch_bounds__(256) void k_wt(const float* __restrict__ W,
                                            u16* __restrict__ Wt, int K, int N) {
  __shared__ __align__(16) u16 T[64][72];
  const int nb = blockIdx.x * 64;
  const int kb = blockIdx.y * 64;
#pragma unroll
  for (int p = 0; p < 4; ++p) {
    const int r = p * 16 + (threadIdx.x >> 4);      // k within tile
    const int c = (threadIdx.x & 15) * 4;           // n within tile
    float4 v = *(const float4*)(W + (size_t)(kb + r) * N + nb + c);
    T[c + 0][r] = f2bf(v.x); T[c + 1][r] = f2bf(v.y);
    T[c + 2][r] = f2bf(v.z); T[c + 3][r] = f2bf(v.w);
  }
  __syncthreads();
  const int cc = (threadIdx.x & 7) * 8;
#pragma unroll
  for (int p = 0; p < 2; ++p) {
    const int rr = p * 32 + (threadIdx.x >> 3);
    *(u16x8*)(Wt + (size_t)(nb + rr) * K + kb + cc) = *(const u16x8*)&T[rr][cc];
  }
}

// ---------------- MFMA GEMM: C[M x Nc] = A[M x K]bf16 @ Wt[Nc x K]bf16^T -----
// BM=128 fixed, BN in {64,128}. MODE: 0=+bias, 1=gelu(+bias), 2=0.5*(+bias)+res,
// 3=(+bias)+res. OUTBF: emit bf16 else fp32.
template<int BN, int MODE, bool OUTBF>
__global__ __launch_bounds__(256) void k_gemm_mfma(const u16* __restrict__ A,
                                                   const u16* __restrict__ Wt,
                                                   const float* __restrict__ bias,
                                                   const float* __restrict__ res,
                                                   void* __restrict__ Cv,
                                                   int K, int Nc) {
  constexpr int BM = 128;
  constexpr int CT = BN / 32;           // col 16-tiles per wave
  __shared__ __align__(16) u16 As[BM * 32];
  __shared__ __align__(16) u16 Bs[BN * 32];
  const int lane = threadIdx.x & 63;
  const int w    = threadIdx.x >> 6;
  const int rowBase = blockIdx.y * BM;
  const int colBase = blockIdx.x * BN;
  const int l15 = lane & 15, quad = lane >> 4;
  const int wr = w >> 1, wc = w & 1;

  f32x4 acc[4][CT];
#pragma unroll
  for (int i = 0; i < 4; ++i)
#pragma unroll
    for (int j = 0; j < CT; ++j) acc[i][j] = (f32x4){0.f, 0.f, 0.f, 0.f};

  for (int k0 = 0; k0 < K; k0 += 32) {
    // stage A: 128x32 bf16 = 512 chunks of 16B; 2 insts/wave
#pragma unroll
    for (int s = 0; s < 2; ++s) {
      const int cbase = (w * 2 + s) * 64;
      const int c = cbase + lane;
      const int r = c >> 2, ko = (c & 3) * 8;
      __builtin_amdgcn_global_load_lds(
          GPTR(A + (size_t)(rowBase + r) * K + k0 + ko),
          LPTR((char*)As + (size_t)cbase * 16), 16, 0, 0);
    }
    // stage B: BN x 32 bf16
    if (BN == 128) {
#pragma unroll
      for (int s = 0; s < 2; ++s) {
        const int cbase = (w * 2 + s) * 64;
        const int c = cbase + lane;
        const int r = c >> 2, ko = (c & 3) * 8;
        __builtin_amdgcn_global_load_lds(
            GPTR(Wt + (size_t)(colBase + r) * K + k0 + ko),
            LPTR((char*)Bs + (size_t)cbase * 16), 16, 0, 0);
      }
    } else {
      const int cbase = w * 64;
      const int c = cbase + lane;
      const int r = c >> 2, ko = (c & 3) * 8;
      __builtin_amdgcn_global_load_lds(
          GPTR(Wt + (size_t)(colBase + r) * K + k0 + ko),
          LPTR((char*)Bs + (size_t)cbase * 16), 16, 0, 0);
    }
    __syncthreads();

    bf16x8 aF[4], bF[CT];
#pragma unroll
    for (int rt = 0; rt < 4; ++rt)
      aF[rt] = *(const bf16x8*)&As[(wr * 64 + rt * 16 + l15) * 32 + quad * 8];
#pragma unroll
    for (int ct = 0; ct < CT; ++ct)
      bF[ct] = *(const bf16x8*)&Bs[(wc * (BN / 2) + ct * 16 + l15) * 32 + quad * 8];
#pragma unroll
    for (int rt = 0; rt < 4; ++rt)
#pragma unroll
      for (int ct = 0; ct < CT; ++ct)
        acc[rt][ct] = __builtin_amdgcn_mfma_f32_16x16x32_bf16(aF[rt], bF[ct],
                                                              acc[rt][ct], 0, 0, 0);
    __syncthreads();
  }

  // epilogue
#pragma unroll
  for (int ct = 0; ct < CT; ++ct) {
    const int col = colBase + wc * (BN / 2) + ct * 16 + l15;
    const float bv = bias ? bias[col] : 0.f;
#pragma unroll
    for (int rt = 0; rt < 4; ++rt) {
#pragma unroll
      for (int r = 0; r < 4; ++r) {
        const int row = rowBase + wr * 64 + rt * 16 + quad * 4 + r;
        float v = acc[rt][ct][r] + bv;
        if (MODE == 1) v = geluf(v);
        else if (MODE == 2) v = 0.5f * v + res[(size_t)row * Nc + col];
        else if (MODE == 3) v = v + res[(size_t)row * Nc + col];
        if (OUTBF) ((u16*)Cv)[(size_t)row * Nc + col] = f2bf(v);
        else       ((float*)Cv)[(size_t)row * Nc + col] = v;
      }
    }
  }
}

// ---------------- qkv split + q/k rmsnorm + kv emit ----------------
__global__ __launch_bounds__(768) void k_qkv_post(const float* __restrict__ qkv,
                                                  const float* __restrict__ qw,
                                                  const float* __restrict__ kw,
                                                  float* __restrict__ qout,
                                                  float* __restrict__ kvout) {
  const int row = blockIdx.x;             // b*Nn + n
  const int b = row >> 11;
  const int n = row & 2047;
  const int h = threadIdx.x >> 6;
  const int d = threadIdx.x & 63;
  const float* src = qkv + (size_t)row * (3 * DM) + h * 192 + d * 3;
  const float q = src[0], k = src[1], v = src[2];
  float sq = q * q, sk = k * k;
#pragma unroll
  for (int off = 32; off > 0; off >>= 1) {
    sq += __shfl_xor(sq, off, 64);
    sk += __shfl_xor(sk, off, 64);
  }
  const float qs = rsqrtf(sq * (1.0f / 64.0f) + EPSF);
  const float ks = rsqrtf(sk * (1.0f / 64.0f) + EPSF);
  const float qn = q * qs * qw[d];
  const float kn = k * ks * kw[d];
  qout[(size_t)row * DM + h * 64 + d] = qn;
  const size_t kvbase = ((size_t)b * KVL + (CACHE + n)) * (2 * DM) + h * 64 + d;
  kvout[kvbase] = kn;
  kvout[kvbase + DM] = v;
}

// ---------------- copy cached_kv into kv output rows 0..511 ----------------
__global__ __launch_bounds__(256) void k_copy_cache(const float* __restrict__ cached,
                                                    float* __restrict__ kvout) {
  const int e = blockIdx.x * 256 + threadIdx.x;
  const int flat = e * 4;
  const int b = flat / (CACHE * 2 * DM);
  const int r = flat - b * (CACHE * 2 * DM);
  float4 v = *(const float4*)(cached + (size_t)b * (CACHE * 2 * DM) + r);
  *(float4*)(kvout + (size_t)b * (KVL * 2 * DM) + r) = v;
}

// ---------------- RoPE (emit bf16) ----------------
__global__ __launch_bounds__(256) void k_rope_q(const float* __restrict__ q,
                                                u16* __restrict__ qbf) {
  const int hrow = blockIdx.x * 4 + (threadIdx.x >> 6);
  const int d = threadIdx.x & 63;
  const int n = (hrow / NH) & (Nn - 1);
  const float pos = (float)(CACHE + n);
  const float x = q[(size_t)hrow * 64 + d];
  const int j = d & 31;
  const float inv = powf(10000.0f, -(float)j * (1.0f / 32.0f));
  float s, c;
  sincosf(pos * inv, &s, &c);
  const float other = __shfl_xor(x, 32, 64);
  const float rot = (d < 32) ? -other : other;
  qbf[(size_t)hrow * 64 + d] = f2bf(x * c + rot * s);
}

__global__ __launch_bounds__(256) void k_rope_k(const float* __restrict__ kvout,
                                                u16* __restrict__ krotbf) {
  const int hrow = blockIdx.x * 4 + (threadIdx.x >> 6);  // (b,t,h)
  const int d = threadIdx.x & 63;
  const int b = hrow / (KVL * NH);
  const int rem = hrow - b * (KVL * NH);
  const int t = rem / NH;
  const int h = rem - t * NH;
  const float x = kvout[((size_t)b * KVL + t) * (2 * DM) + h * 64 + d];
  const int j = d & 31;
  const float inv = powf(10000.0f, -(float)j * (1.0f / 32.0f));
  float s, c;
  sincosf((float)t * inv, &s, &c);
  const float other = __shfl_xor(x, 32, 64);
  const float rot = (d < 32) ? -other : other;
  krotbf[(size_t)hrow * 64 + d] = f2bf(x * c + rot * s);
}

// ---------------- V transpose: (B,KVL,H,64) f32 -> vtbf (B,H,64,KVL) bf16 ----
__global__ __launch_bounds__(256) void k_vt(const float* __restrict__ kvout,
                                            u16* __restrict__ vtbf) {
  __shared__ __align__(16) u16 T[64][72];
  const int bh = blockIdx.x / 40;
  const int tb = blockIdx.x % 40;
  const int b = bh / NH, h = bh % NH;
  const int t0 = tb * 64;
  {
    const int tloc = threadIdx.x >> 2;
    const int dg = (threadIdx.x & 3) * 16;
    const float* src = kvout + ((size_t)b * KVL + t0 + tloc) * (2 * DM) + DM + h * 64 + dg;
    float4 v0 = *(const float4*)(src);
    float4 v1 = *(const float4*)(src + 4);
    float4 v2 = *(const float4*)(src + 8);
    float4 v3 = *(const float4*)(src + 12);
    T[dg + 0][tloc] = f2bf(v0.x);  T[dg + 1][tloc] = f2bf(v0.y);
    T[dg + 2][tloc] = f2bf(v0.z);  T[dg + 3][tloc] = f2bf(v0.w);
    T[dg + 4][tloc] = f2bf(v1.x);  T[dg + 5][tloc] = f2bf(v1.y);
    T[dg + 6][tloc] = f2bf(v1.z);  T[dg + 7][tloc] = f2bf(v1.w);
    T[dg + 8][tloc] = f2bf(v2.x);  T[dg + 9][tloc] = f2bf(v2.y);
    T[dg + 10][tloc] = f2bf(v2.z); T[dg + 11][tloc] = f2bf(v2.w);
    T[dg + 12][tloc] = f2bf(v3.x); T[dg + 13][tloc] = f2bf(v3.y);
    T[dg + 14][tloc] = f2bf(v3.z); T[dg + 15][tloc] = f2bf(v3.w);
  }
  __syncthreads();
  const int d = threadIdx.x >> 2;
  const int kg = (threadIdx.x & 3) * 16;
  u16x8 a = *(const u16x8*)&T[d][kg];
  u16x8 b8 = *(const u16x8*)&T[d][kg + 8];
  u16* dst = vtbf + ((size_t)(b * NH + h) * 64 + d) * KVL + t0 + kg;
  *(u16x8*)dst = a;
  *(u16x8*)(dst + 8) = b8;
}

// ---------------- MFMA flash attention (bf16 out) ----------------
__global__ __launch_bounds__(256) void k_attn_mfma(const u16* __restrict__ qbf,
                                                   const u16* __restrict__ krotbf,
                                                   const u16* __restrict__ vtbf,
                                                   u16* __restrict__ out) {
  __shared__ __align__(16) u16 Ks[64][72];
  __shared__ __align__(16) u16 Vs[64][72];
  __shared__ __align__(16) u16 Ps[4][16][72];
  const int lane = threadIdx.x & 63;
  const int wid  = threadIdx.x >> 6;
  const int qblk = blockIdx.x & 31;
  const int bh   = blockIdx.x >> 5;
  const int b = bh / NH, h = bh % NH;
  const int q0 = qblk * 64 + wid * 16;
  const int l15 = lane & 15;
  const int quad = lane >> 4;

  const u16* qptr = qbf + ((size_t)(b * Nn + q0 + l15) * NH + h) * 64 + quad * 8;
  const bf16x8 aQ0 = *(const bf16x8*)qptr;
  const bf16x8 aQ1 = *(const bf16x8*)(qptr + 32);

  f32x4 O[4] = {};
  float m_[4] = {-1e30f, -1e30f, -1e30f, -1e30f};
  float l_[4] = {};

  for (int kv0 = 0; kv0 < KVL; kv0 += 64) {
    __syncthreads();
    {
      int c = threadIdx.x;
#pragma unroll
      for (int it = 0; it < 2; ++it, c += 256) {
        const int r = c >> 3, part = (c & 7) * 8;
        *(u16x8*)&Ks[r][part] =
            *(const u16x8*)(krotbf + ((size_t)(b * KVL + kv0 + r) * NH + h) * 64 + part);
        *(u16x8*)&Vs[r][part] =
            *(const u16x8*)(vtbf + ((size_t)(b * NH + h) * 64 + r) * KVL + kv0 + part);
      }
    }
    __syncthreads();

    float s[4][4];
#pragma unroll
    for (int nt = 0; nt < 4; ++nt) {
      const bf16x8 bK0 = *(const bf16x8*)&Ks[nt * 16 + l15][quad * 8];
      const bf16x8 bK1 = *(const bf16x8*)&Ks[nt * 16 + l15][32 + quad * 8];
      f32x4 c = {};
      c = __builtin_amdgcn_mfma_f32_16x16x32_bf16(aQ0, bK0, c, 0, 0, 0);
      c = __builtin_amdgcn_mfma_f32_16x16x32_bf16(aQ1, bK1, c, 0, 0, 0);
#pragma unroll
      for (int r = 0; r < 4; ++r) s[nt][r] = c[r] * 0.125f;
    }

#pragma unroll
    for (int r = 0; r < 4; ++r) {
      float t = fmaxf(fmaxf(s[0][r], s[1][r]), fmaxf(s[2][r], s[3][r]));
      t = fmaxf(t, __shfl_xor(t, 1, 64));
      t = fmaxf(t, __shfl_xor(t, 2, 64));
      t = fmaxf(t, __shfl_xor(t, 4, 64));
      t = fmaxf(t, __shfl_xor(t, 8, 64));
      const float mnew = fmaxf(m_[r], t);
      const float alpha = __expf(m_[r] - mnew);
      float rs = 0.f;
#pragma unroll
      for (int nt = 0; nt < 4; ++nt) { s[nt][r] = __expf(s[nt][r] - mnew); rs += s[nt][r]; }
      rs += __shfl_xor(rs, 1, 64);
      rs += __shfl_xor(rs, 2, 64);
      rs += __shfl_xor(rs, 4, 64);
      rs += __shfl_xor(rs, 8, 64);
      l_[r] = alpha * l_[r] + rs;
      m_[r] = mnew;
#pragma unroll
      for (int ot = 0; ot < 4; ++ot) O[ot][r] *= alpha;
    }

#pragma unroll
    for (int nt = 0; nt < 4; ++nt)
#pragma unroll
      for (int r = 0; r < 4; ++r)
        Ps[wid][quad * 4 + r][nt * 16 + l15] = f2bf(s[nt][r]);
    __syncthreads();

#pragma unroll
    for (int kt = 0; kt < 2; ++kt) {
      const bf16x8 aP = *(const bf16x8*)&Ps[wid][l15][kt * 32 + quad * 8];
#pragma unroll
      for (int ot = 0; ot < 4; ++ot) {
        const bf16x8 bV = *(const bf16x8*)&Vs[ot * 16 + l15][kt * 32 + quad * 8];
        O[ot] = __builtin_amdgcn_mfma_f32_16x16x32_bf16(aP, bV, O[ot], 0, 0, 0);
      }
    }
  }

#pragma unroll
  for (int r = 0; r < 4; ++r) {
    const float inv = 1.0f / l_[r];
    const int q = q0 + quad * 4 + r;
    u16* op = out + ((size_t)(b * Nn + q)) * DM + h * 64;
#pragma unroll
    for (int ot = 0; ot < 4; ++ot) op[ot * 16 + l15] = f2bf(O[ot][r] * inv);
  }
}

// ---------------- fused GLU + depthwise conv + BN partial stats ----------------
// block: 64 n x 64 ch tile; grid (DM/64, Nn/64, B).
__global__ __launch_bounds__(256) void k_dwconv2(const u16* __restrict__ pw1,
                                                 const float* __restrict__ w,
                                                 const float* __restrict__ bsd,
                                                 float* __restrict__ out,
                                                 float* __restrict__ stats) {
  __shared__ float S[94][68];
  __shared__ float Wl[31][64];
  const int cb = blockIdx.x * 64;
  const int n0 = blockIdx.y * 64;
  const int b  = blockIdx.z;
  // stage silu(a,gate) tile with halo
  for (int idx = threadIdx.x; idx < 94 * 16; idx += 256) {
    const int r = idx >> 4, cg = (idx & 15) * 4;
    const int n = n0 - 15 + r;
    float4 v = make_float4(0.f, 0.f, 0.f, 0.f);
    if (n >= 0 && n < Nn) {
      const u16* p = pw1 + ((size_t)(b * Nn + n)) * (2 * DM) + cb + cg;
      u16x4 av = *(const u16x4*)(p);
      u16x4 gv = *(const u16x4*)(p + DM);
      v.x = bf2f(av[0]) * sigmoidf_(bf2f(gv[0]));
      v.y = bf2f(av[1]) * sigmoidf_(bf2f(gv[1]));
      v.z = bf2f(av[2]) * sigmoidf_(bf2f(gv[2]));
      v.w = bf2f(av[3]) * sigmoidf_(bf2f(gv[3]));
    }
    *(float4*)&S[r][cg] = v;
  }
  for (int idx = threadIdx.x; idx < 31 * 64; idx += 256) {
    const int c = idx & 63, tap = idx >> 6;
    Wl[tap][c] = w[(size_t)(cb + c) * 31 + tap];
  }
  __syncthreads();

  const int cg  = (threadIdx.x & 15) * 4;
  const int nl0 = threadIdx.x >> 4;
  const float4 b4 = *(const float4*)(bsd + cb + cg);
  float sum[4] = {0.f, 0.f, 0.f, 0.f};
  float sq[4]  = {0.f, 0.f, 0.f, 0.f};
#pragma unroll
  for (int p = 0; p < 4; ++p) {
    const int nl = p * 16 + nl0;
    float a0 = b4.x, a1 = b4.y, a2 = b4.z, a3 = b4.w;
#pragma unroll
    for (int t = 0; t < 31; ++t) {
      const float4 sv = *(const float4*)&S[nl + t][cg];
      const float4 wv = *(const float4*)&Wl[t][cg & 63];
      a0 = fmaf(sv.x, wv.x, a0); a1 = fmaf(sv.y, wv.y, a1);
      a2 = fmaf(sv.z, wv.z, a2); a3 = fmaf(sv.w, wv.w, a3);
    }
    *(float4*)(out + ((size_t)(b * Nn + n0 + nl)) * DM + cb + cg) =
        make_float4(a0, a1, a2, a3);
    sum[0] += a0; sum[1] += a1; sum[2] += a2; sum[3] += a3;
    sq[0] = fmaf(a0, a0, sq[0]); sq[1] = fmaf(a1, a1, sq[1]);
    sq[2] = fmaf(a2, a2, sq[2]); sq[3] = fmaf(a3, a3, sq[3]);
  }
  __syncthreads();
  *(float4*)&S[nl0][cg]      = make_float4(sum[0], sum[1], sum[2], sum[3]);
  *(float4*)&S[16 + nl0][cg] = make_float4(sq[0], sq[1], sq[2], sq[3]);
  __syncthreads();
  if (threadIdx.x < 64) {
    const int c = threadIdx.x;
    float s = 0.f, q = 0.f;
#pragma unroll
    for (int i = 0; i < 16; ++i) { s += S[i][c]; q += S[16 + i][c]; }
    atomicAdd(&stats[cb + c], s);
    atomicAdd(&stats[DM + cb + c], q);
  }
}

__global__ __launch_bounds__(256) void k_zero(float* __restrict__ p, int n) {
  const int i = blockIdx.x * 256 + threadIdx.x;
  if (i < n) p[i] = 0.f;
}

// BN apply + silu, bf16 out (feeds pw2 GEMM)
__global__ __launch_bounds__(256) void k_bn_apply(const float* __restrict__ x,
                                                  const float* __restrict__ stats,
                                                  const float* __restrict__ g,
                                                  const float* __restrict__ bb,
                                                  u16* __restrict__ out) {
  const int idx = blockIdx.x * 256 + threadIdx.x;
  const int c = idx % DM;
  const float mean = stats[c] * (1.0f / (float)RR);
  const float var = stats[DM + c] * (1.0f / (float)RR) - mean * mean;
  float y = (x[idx] - mean) * rsqrtf(var + EPSF) * g[c] + bb[c];
  out[idx] = f2bf(y * sigmoidf_(y));
}

// ---------------- launch ----------------
extern "C" void kernel_launch(void* const* d_in, const int* in_sizes, int n_in,
                              void* d_out, int out_size, void* d_ws, size_t ws_size,
                              hipStream_t stream) {
  const float* x       = (const float*)d_in[0];
  const float* cached  = (const float*)d_in[4];
  const float* ff1_nw  = (const float*)d_in[5];
  const float* ff1_w1  = (const float*)d_in[6];
  const float* ff1_b1  = (const float*)d_in[7];
  const float* ff1_w2  = (const float*)d_in[8];
  const float* ff1_b2  = (const float*)d_in[9];
  const float* attn_nw = (const float*)d_in[10];
  const float* qkv_w   = (const float*)d_in[11];
  const float* out_w   = (const float*)d_in[12];
  const float* q_nw    = (const float*)d_in[13];
  const float* k_nw    = (const float*)d_in[14];
  const float* conv_nw = (const float*)d_in[15];
  const float* pw1_w   = (const float*)d_in[16];
  const float* pw1_b   = (const float*)d_in[17];
  const float* dw_w    = (const float*)d_in[18];
  const float* dw_b    = (const float*)d_in[19];
  const float* bn_g    = (const float*)d_in[20];
  const float* bn_b    = (const float*)d_in[21];
  const float* pw2_w   = (const float*)d_in[22];
  const float* pw2_b   = (const float*)d_in[23];
  const float* ff2_nw  = (const float*)d_in[24];
  const float* ff2_w1  = (const float*)d_in[25];
  const float* ff2_b1  = (const float*)d_in[26];
  const float* ff2_w2  = (const float*)d_in[27];
  const float* ff2_b2  = (const float*)d_in[28];
  const float* out_nw  = (const float*)d_in[29];

  float* out_x  = (float*)d_out;
  float* out_kv = out_x + (size_t)RR * DM;

  // ---- workspace layout (~143.5 MB) ----
  u16* wt_ff1w1 = (u16*)d_ws;                          // 3072 x 768
  u16* wt_ff1w2 = wt_ff1w1 + (size_t)3072 * 768;       // 768 x 3072
  u16* wt_qkv   = wt_ff1w2 + (size_t)768 * 3072;       // 2304 x 768
  u16* wt_out   = wt_qkv   + (size_t)2304 * 768;       // 768 x 768
  u16* wt_pw1   = wt_out   + (size_t)768 * 768;        // 1536 x 768
  u16* wt_pw2   = wt_pw1   + (size_t)1536 * 768;       // 768 x 768
  u16* wt_ff2w1 = wt_pw2   + (size_t)768 * 768;        // 3072 x 768
  u16* wt_ff2w2 = wt_ff2w1 + (size_t)3072 * 768;       // 768 x 3072
  u16* abuf     = wt_ff2w2 + (size_t)768 * 3072;       // RR x 768 bf16
  u16* hbuf     = abuf + (size_t)RR * DM;              // RR x 3072 bf16 (alias pw1out)
  float* xA     = (float*)(hbuf + (size_t)RR * FFD);   // RR x 768 f32
  float* xB     = xA + (size_t)RR * DM;                // RR x 768 f32 (alias qfp)
  float* qkvbuf = xB + (size_t)RR * DM;                // RR x 2304 f32
  u16* qbf      = (u16*)(qkvbuf + (size_t)RR * 3 * DM);
  u16* krotbf   = qbf + (size_t)RR * DM;
  u16* vtbf     = krotbf + (size_t)Bc * KVL * DM;
  float* bn_stats = (float*)(vtbf + (size_t)Bc * KVL * DM);
  // aliases inside qkvbuf region (lifetimes disjoint from qkv itself)
  u16* attnout  = (u16*)qkvbuf;                        // RR x 768 bf16
  float* dwout  = qkvbuf;                              // RR x 768 f32
  u16* bnout    = (u16*)(qkvbuf + (size_t)RR * DM);    // RR x 768 bf16
  float* qfp    = xB;

  const dim3 blk(256);
  // ---- weight prep (bf16, transposed) ----
  k_wt<<<dim3(48, 12), blk, 0, stream>>>(ff1_w1, wt_ff1w1, DM, FFD);
  k_wt<<<dim3(12, 48), blk, 0, stream>>>(ff1_w2, wt_ff1w2, FFD, DM);
  k_wt<<<dim3(36, 12), blk, 0, stream>>>(qkv_w, wt_qkv, DM, 3 * DM);
  k_wt<<<dim3(12, 12), blk, 0, stream>>>(out_w, wt_out, DM, DM);
  k_wt<<<dim3(24, 12), blk, 0, stream>>>(pw1_w, wt_pw1, DM, 2 * DM);
  k_wt<<<dim3(12, 12), blk, 0, stream>>>(pw2_w, wt_pw2, DM, DM);
  k_wt<<<dim3(48, 12), blk, 0, stream>>>(ff2_w1, wt_ff2w1, DM, FFD);
  k_wt<<<dim3(12, 48), blk, 0, stream>>>(ff2_w2, wt_ff2w2, FFD, DM);

  // ---- FF1: x1 = 0.5*(gelu(rms(x)@w1+b1)@w2+b2) + x
  k_rmsnorm2<true><<<RR, blk, 0, stream>>>(x, ff1_nw, abuf, DM);
  k_gemm_mfma<128, 1, true><<<dim3(FFD / 128, RR / 128), blk, 0, stream>>>(
      abuf, wt_ff1w1, ff1_b1, nullptr, hbuf, DM, FFD);
  k_gemm_mfma<64, 2, false><<<dim3(DM / 64, RR / 128), blk, 0, stream>>>(
      hbuf, wt_ff1w2, ff1_b2, x, xA, FFD, DM);
  // ---- Attention
  k_rmsnorm2<true><<<RR, blk, 0, stream>>>(xA, attn_nw, abuf, DM);
  k_gemm_mfma<128, 0, false><<<dim3(3 * DM / 128, RR / 128), blk, 0, stream>>>(
      abuf, wt_qkv, nullptr, nullptr, qkvbuf, DM, 3 * DM);
  k_qkv_post<<<RR, 768, 0, stream>>>(qkvbuf, q_nw, k_nw, qfp, out_kv);
  k_copy_cache<<<(Bc * CACHE * 2 * DM) / 4 / 256, blk, 0, stream>>>(cached, out_kv);
  k_rope_q<<<RR * NH / 4, blk, 0, stream>>>(qfp, qbf);
  k_rope_k<<<Bc * KVL * NH / 4, blk, 0, stream>>>(out_kv, krotbf);
  k_vt<<<Bc * NH * (KVL / 64), blk, 0, stream>>>(out_kv, vtbf);
  k_attn_mfma<<<Bc * NH * (Nn / 64), blk, 0, stream>>>(qbf, krotbf, vtbf, attnout);
  k_gemm_mfma<64, 3, false><<<dim3(DM / 64, RR / 128), blk, 0, stream>>>(
      attnout, wt_out, nullptr, xA, xB, DM, DM);          // x2
  // ---- Conv module
  k_rmsnorm2<true><<<RR, blk, 0, stream>>>(xB, conv_nw, abuf, DM);
  k_gemm_mfma<128, 0, true><<<dim3(2 * DM / 128, RR / 128), blk, 0, stream>>>(
      abuf, wt_pw1, pw1_b, nullptr, hbuf, DM, 2 * DM);    // pw1out (bf16) in hbuf
  k_zero<<<6, blk, 0, stream>>>(bn_stats, 2 * DM);
  k_dwconv2<<<dim3(DM / 64, Nn / 64, Bc), blk, 0, stream>>>(hbuf, dw_w, dw_b,
                                                            dwout, bn_stats);
  k_bn_apply<<<RR * DM / 256, blk, 0, stream>>>(dwout, bn_stats, bn_g, bn_b, bnout);
  k_gemm_mfma<64, 0, false><<<dim3(DM / 64, RR / 128), blk, 0, stream>>>(
      bnout, wt_pw2, pw2_b, nullptr, xA, DM, DM);         // x3
  // ---- FF2
  k_rmsnorm2<true><<<RR, blk, 0, stream>>>(xA, ff2_nw, abuf, DM);
  k_gemm_mfma<128, 1, true><<<dim3(FFD / 128, RR / 128), blk, 0, stream>>>(
      abuf, wt_ff2w1, ff2_b1, nullptr, hbuf, DM, FFD);
  k_gemm_mfma<64, 2, false><<<dim3(DM / 64, RR / 128), blk, 0, stream>>>(
      hbuf, wt_ff2w2, ff2_b2, xA, xB, FFD, DM);           // x4
  // ---- final norm -> output 0
  k_rmsnorm2<false><<<RR, blk, 0, stream>>>(xB, out_nw, out_x, DM);
}

// Round 4
// 605.735 us; speedup vs baseline: 7.9164x; 1.2275x over previous
//
#include <hip/hip_runtime.h>
#include <hip/hip_bf16.h>
#include <math.h>

// ---------------- constants ----------------
namespace {
constexpr int Bc   = 2;
constexpr int Nn   = 2048;
constexpr int CACHE= 512;
constexpr int KVL  = 2560;      // CACHE + Nn
constexpr int DM   = 768;
constexpr int NH   = 12;
constexpr int HD   = 64;
constexpr int FFD  = 3072;
constexpr int RR   = Bc * Nn;   // 4096 rows
}
#define EPSF 1e-5f

typedef unsigned short u16;
typedef __bf16 bf16x8 __attribute__((ext_vector_type(8)));
typedef float  f32x4  __attribute__((ext_vector_type(4)));
typedef u16    u16x8  __attribute__((ext_vector_type(8)));
typedef u16    u16x4  __attribute__((ext_vector_type(4)));

#define GPTR(p) ((const __attribute__((address_space(1))) void*)(p))
#define LPTR(p) ((__attribute__((address_space(3))) void*)(p))

// ---------------- helpers ----------------
__device__ __forceinline__ float geluf(float x) {
  float x3 = x * x * x;
  float t  = tanhf(0.7978845608028654f * (x + 0.044715f * x3));
  return 0.5f * x * (1.0f + t);
}
__device__ __forceinline__ float sigmoidf_(float x) {
  return 1.0f / (1.0f + __expf(-x));
}
__device__ __forceinline__ u16 f2bf(float x) {
  union { float f; unsigned u; } v; v.f = x;
  unsigned r = (v.u + 0x7fffu + ((v.u >> 16) & 1u)) >> 16;
  return (u16)r;
}
__device__ __forceinline__ float bf2f(u16 u) {
  union { unsigned u; float f; } v; v.u = ((unsigned)u) << 16;
  return v.f;
}

// ---------------- rmsnorm: one block per row; bf16 or fp32 out ----------------
template<bool BF>
__global__ __launch_bounds__(256) void k_rmsnorm2(const float* __restrict__ in,
                                                  const float* __restrict__ w,
                                                  void* __restrict__ outv, int D) {
  const int row = blockIdx.x;
  const float* x = in + (size_t)row * D;
  float ss = 0.f;
  for (int i = threadIdx.x; i < D; i += 256) { float v = x[i]; ss = fmaf(v, v, ss); }
  __shared__ float red[5];
#pragma unroll
  for (int off = 32; off > 0; off >>= 1) ss += __shfl_down(ss, off, 64);
  if ((threadIdx.x & 63) == 0) red[threadIdx.x >> 6] = ss;
  __syncthreads();
  if (threadIdx.x == 0) red[4] = red[0] + red[1] + red[2] + red[3];
  __syncthreads();
  const float scale = rsqrtf(red[4] * (1.0f / (float)D) + EPSF);
  for (int i = threadIdx.x; i < D; i += 256) {
    const float v = x[i] * scale * w[i];
    if (BF) ((u16*)outv)[(size_t)row * D + i] = f2bf(v);
    else    ((float*)outv)[(size_t)row * D + i] = v;
  }
}

// ---------------- weight prep: W (K x N) f32 -> Wt (N x K) bf16 ----------------
__global__ __launch_bounds__(256) void k_wt(const float* __restrict__ W,
                                            u16* __restrict__ Wt, int K, int N) {
  __shared__ __align__(16) u16 T[64][72];
  const int nb = blockIdx.x * 64;
  const int kb = blockIdx.y * 64;
#pragma unroll
  for (int p = 0; p < 4; ++p) {
    const int r = p * 16 + (threadIdx.x >> 4);      // k within tile
    const int c = (threadIdx.x & 15) * 4;           // n within tile
    float4 v = *(const float4*)(W + (size_t)(kb + r) * N + nb + c);
    T[c + 0][r] = f2bf(v.x); T[c + 1][r] = f2bf(v.y);
    T[c + 2][r] = f2bf(v.z); T[c + 3][r] = f2bf(v.w);
  }
  __syncthreads();
  const int cc = (threadIdx.x & 7) * 8;
#pragma unroll
  for (int p = 0; p < 2; ++p) {
    const int rr = p * 32 + (threadIdx.x >> 3);
    *(u16x8*)(Wt + (size_t)(nb + rr) * K + kb + cc) = *(const u16x8*)&T[rr][cc];
  }
}

// ---------------- MFMA GEMM (m97-style): BM=128, BK=64, XOR-swizzled LDS ------
// C[M x Nc] = A[M x K]bf16 @ Wt[Nc x K]^T. MODE: 0=+bias, 1=gelu, 2=0.5+res, 3=+res.
template<int BN, int MODE, bool OUTBF>
__global__ __launch_bounds__(256) void k_gemm_mfma(const u16* __restrict__ A,
                                                   const u16* __restrict__ Wt,
                                                   const float* __restrict__ bias,
                                                   const float* __restrict__ res,
                                                   void* __restrict__ Cv,
                                                   int K, int Nc) {
  constexpr int BM = 128, BK = 64;
  constexpr int CT = BN / 32;
  __shared__ __align__(16) u16 As[BM * BK];
  __shared__ __align__(16) u16 Bs[BN * BK];
  const int lane = threadIdx.x & 63;
  const int w    = threadIdx.x >> 6;
  const int rowBase = blockIdx.y * BM;
  const int colBase = blockIdx.x * BN;
  const int l15 = lane & 15, quad = lane >> 4;
  const int wr = w >> 1, wc = w & 1;
  const int sw = l15 & 7;

  f32x4 acc[4][CT];
#pragma unroll
  for (int i = 0; i < 4; ++i)
#pragma unroll
    for (int j = 0; j < CT; ++j) acc[i][j] = (f32x4){0.f, 0.f, 0.f, 0.f};

  for (int k0 = 0; k0 < K; k0 += BK) {
    // A: 128x64 bf16 = 1024 16B chunks; chunk c holds (r=c>>3, kc=(c&7)^(r&7))
#pragma unroll
    for (int s = 0; s < 4; ++s) {
      const int cbase = (w * 4 + s) * 64;
      const int c = cbase + lane;
      const int r = c >> 3;
      const int kc = (c & 7) ^ (r & 7);
      __builtin_amdgcn_global_load_lds(
          GPTR(A + (size_t)(rowBase + r) * K + k0 + kc * 8),
          LPTR((char*)As + (size_t)cbase * 16), 16, 0, 0);
    }
#pragma unroll
    for (int s = 0; s < BN / 32; ++s) {
      const int cbase = (w * (BN / 32) + s) * 64;
      const int c = cbase + lane;
      const int r = c >> 3;
      const int kc = (c & 7) ^ (r & 7);
      __builtin_amdgcn_global_load_lds(
          GPTR(Wt + (size_t)(colBase + r) * K + k0 + kc * 8),
          LPTR((char*)Bs + (size_t)cbase * 16), 16, 0, 0);
    }
    __syncthreads();

#pragma unroll
    for (int kk = 0; kk < 2; ++kk) {
      bf16x8 aF[4], bF[CT];
#pragma unroll
      for (int rt = 0; rt < 4; ++rt) {
        const int row = wr * 64 + rt * 16 + l15;
        aF[rt] = *(const bf16x8*)&As[row * BK + (((kk * 4 + quad) ^ sw) * 8)];
      }
#pragma unroll
      for (int ct = 0; ct < CT; ++ct) {
        const int row = wc * (BN / 2) + ct * 16 + l15;
        bF[ct] = *(const bf16x8*)&Bs[row * BK + (((kk * 4 + quad) ^ sw) * 8)];
      }
#pragma unroll
      for (int rt = 0; rt < 4; ++rt)
#pragma unroll
        for (int ct = 0; ct < CT; ++ct)
          acc[rt][ct] = __builtin_amdgcn_mfma_f32_16x16x32_bf16(aF[rt], bF[ct],
                                                                acc[rt][ct], 0, 0, 0);
    }
    __syncthreads();
  }

  // epilogue
#pragma unroll
  for (int ct = 0; ct < CT; ++ct) {
    const int col = colBase + wc * (BN / 2) + ct * 16 + l15;
    const float bv = bias ? bias[col] : 0.f;
#pragma unroll
    for (int rt = 0; rt < 4; ++rt) {
#pragma unroll
      for (int r = 0; r < 4; ++r) {
        const int row = rowBase + wr * 64 + rt * 16 + quad * 4 + r;
        float v = acc[rt][ct][r] + bv;
        if (MODE == 1) v = geluf(v);
        else if (MODE == 2) v = 0.5f * v + res[(size_t)row * Nc + col];
        else if (MODE == 3) v = v + res[(size_t)row * Nc + col];
        if (OUTBF) ((u16*)Cv)[(size_t)row * Nc + col] = f2bf(v);
        else       ((float*)Cv)[(size_t)row * Nc + col] = v;
      }
    }
  }
}

// ---------------- qkv split + q/k rmsnorm + RoPE + kv emit (fused) ------------
// qbf is pre-scaled by 0.125 (attention scale folded in).
__global__ __launch_bounds__(768) void k_qkv_post(const float* __restrict__ qkv,
                                                  const float* __restrict__ qw,
                                                  const float* __restrict__ kw,
                                                  u16* __restrict__ qbf,
                                                  u16* __restrict__ krotbf,
                                                  float* __restrict__ kvout) {
  const int row = blockIdx.x;             // b*Nn + n
  const int b = row >> 11;
  const int n = row & 2047;
  const int h = threadIdx.x >> 6;
  const int d = threadIdx.x & 63;
  const float* src = qkv + (size_t)row * (3 * DM) + h * 192 + d * 3;
  const float q = src[0], k = src[1], v = src[2];
  float sq = q * q, sk = k * k;
#pragma unroll
  for (int off = 32; off > 0; off >>= 1) {
    sq += __shfl_xor(sq, off, 64);
    sk += __shfl_xor(sk, off, 64);
  }
  const float qs = rsqrtf(sq * (1.0f / 64.0f) + EPSF);
  const float ks = rsqrtf(sk * (1.0f / 64.0f) + EPSF);
  const float qn = q * qs * qw[d];
  const float kn = k * ks * kw[d];
  const size_t kvbase = ((size_t)b * KVL + (CACHE + n)) * (2 * DM) + h * 64 + d;
  kvout[kvbase] = kn;
  kvout[kvbase + DM] = v;
  // RoPE (pos = CACHE + n) for q and new-row k
  const int j = d & 31;
  const float inv = powf(10000.0f, -(float)j * (1.0f / 32.0f));
  float s, c;
  sincosf((float)(CACHE + n) * inv, &s, &c);
  const float oq = __shfl_xor(qn, 32, 64);
  const float ok = __shfl_xor(kn, 32, 64);
  const float rq = (d < 32) ? -oq : oq;
  const float rk = (d < 32) ? -ok : ok;
  qbf[((size_t)row * NH + h) * 64 + d] = f2bf((qn * c + rq * s) * 0.125f);
  krotbf[((size_t)(b * KVL + CACHE + n) * NH + h) * 64 + d] = f2bf(kn * c + rk * s);
}

// ---------------- cache rows: copy to out_kv + RoPE k (fused) -----------------
__global__ __launch_bounds__(768) void k_cache_prep(const float* __restrict__ cached,
                                                    float* __restrict__ kvout,
                                                    u16* __restrict__ krotbf) {
  const int row = blockIdx.x;            // b*CACHE + t
  const int b = row / CACHE, t = row - b * CACHE;
  const int h = threadIdx.x >> 6;
  const int d = threadIdx.x & 63;
  const float k = cached[((size_t)row * 2 + 0) * DM + h * 64 + d];
  const float v = cached[((size_t)row * 2 + 1) * DM + h * 64 + d];
  const size_t kb = ((size_t)b * KVL + t) * (2 * DM) + h * 64 + d;
  kvout[kb] = k;
  kvout[kb + DM] = v;
  const int j = d & 31;
  const float inv = powf(10000.0f, -(float)j * (1.0f / 32.0f));
  float s, c;
  sincosf((float)t * inv, &s, &c);
  const float ok = __shfl_xor(k, 32, 64);
  const float rk = (d < 32) ? -ok : ok;
  krotbf[((size_t)(b * KVL + t) * NH + h) * 64 + d] = f2bf(k * c + rk * s);
}

// ---------------- V transpose: (B,KVL,H,64) f32 -> vtbf (B,H,64,KVL) bf16 ----
__global__ __launch_bounds__(256) void k_vt(const float* __restrict__ kvout,
                                            u16* __restrict__ vtbf) {
  __shared__ __align__(16) u16 T[64][72];
  const int bh = blockIdx.x / 40;
  const int tb = blockIdx.x % 40;
  const int b = bh / NH, h = bh % NH;
  const int t0 = tb * 64;
  {
    const int tloc = threadIdx.x >> 2;
    const int dg = (threadIdx.x & 3) * 16;
    const float* src = kvout + ((size_t)b * KVL + t0 + tloc) * (2 * DM) + DM + h * 64 + dg;
    float4 v0 = *(const float4*)(src);
    float4 v1 = *(const float4*)(src + 4);
    float4 v2 = *(const float4*)(src + 8);
    float4 v3 = *(const float4*)(src + 12);
    T[dg + 0][tloc] = f2bf(v0.x);  T[dg + 1][tloc] = f2bf(v0.y);
    T[dg + 2][tloc] = f2bf(v0.z);  T[dg + 3][tloc] = f2bf(v0.w);
    T[dg + 4][tloc] = f2bf(v1.x);  T[dg + 5][tloc] = f2bf(v1.y);
    T[dg + 6][tloc] = f2bf(v1.z);  T[dg + 7][tloc] = f2bf(v1.w);
    T[dg + 8][tloc] = f2bf(v2.x);  T[dg + 9][tloc] = f2bf(v2.y);
    T[dg + 10][tloc] = f2bf(v2.z); T[dg + 11][tloc] = f2bf(v2.w);
    T[dg + 12][tloc] = f2bf(v3.x); T[dg + 13][tloc] = f2bf(v3.y);
    T[dg + 14][tloc] = f2bf(v3.z); T[dg + 15][tloc] = f2bf(v3.w);
  }
  __syncthreads();
  const int d = threadIdx.x >> 2;
  const int kg = (threadIdx.x & 3) * 16;
  u16x8 a = *(const u16x8*)&T[d][kg];
  u16x8 b8 = *(const u16x8*)&T[d][kg + 8];
  u16* dst = vtbf + ((size_t)(b * NH + h) * 64 + d) * KVL + t0 + kg;
  *(u16x8*)dst = a;
  *(u16x8*)(dst + 8) = b8;
}

// ---------------- MFMA flash attention v2 ----------------
// Fixed-max softmax (scores bounded by |q||k|/8 ~ 8), S^T formulation,
// KV-split x2, glds staging with XOR swizzle. Outputs UNNORMALIZED partials.
__global__ __launch_bounds__(256) void k_attn2(const u16* __restrict__ qbf,
                                               const u16* __restrict__ krotbf,
                                               const u16* __restrict__ vtbf,
                                               float* __restrict__ Apart,
                                               float* __restrict__ lpart) {
  __shared__ __align__(16) u16 Ks[64 * 64];     // [key][dim], swizzled chunks
  __shared__ __align__(16) u16 Vs[64 * 64];     // [dim][key], swizzled chunks
  __shared__ __align__(16) u16 Ps[4][16][80];   // per-wave P^T: [q][key]
  const int lane = threadIdx.x & 63;
  const int wid  = threadIdx.x >> 6;
  const int sp   = blockIdx.x & 1;
  const int rest = blockIdx.x >> 1;
  const int qblk = rest & 31;
  const int bh   = rest >> 5;
  const int b = bh / NH, h = bh % NH;
  const int q0 = qblk * 64 + wid * 16;
  const int l15 = lane & 15;
  const int quad = lane >> 4;
  const int sw = l15 & 7;

  // Q as B-operand: lane l15 = q, quad*8+j = dim (pre-scaled by 0.125)
  const u16* qp = qbf + ((size_t)(b * Nn + q0 + l15) * NH + h) * 64 + quad * 8;
  const bf16x8 bQ0 = *(const bf16x8*)qp;
  const bf16x8 bQ1 = *(const bf16x8*)(qp + 32);

  f32x4 O[4] = {};        // O^T: d = ot*16 + quad*4 + r, q = l15
  float l_lane = 0.f;

  const u16* kbase = krotbf + ((size_t)b * KVL * NH + h) * 64;
  const u16* vbase = vtbf + ((size_t)(b * NH + h) * 64) * KVL;

  const int tbeg = sp * (KVL / 2);
  for (int t0 = tbeg; t0 < tbeg + KVL / 2; t0 += 64) {
    __syncthreads();
    // stage K (64 keys x 64 dims) and Vt (64 dims x 64 keys): 512 chunks each
#pragma unroll
    for (int it = 0; it < 2; ++it) {
      const int cbase = (wid * 2 + it) * 64;
      const int c = cbase + lane;
      const int r = c >> 3;
      const int kc = (c & 7) ^ (r & 7);
      __builtin_amdgcn_global_load_lds(
          GPTR(kbase + (size_t)(t0 + r) * (NH * 64) + kc * 8),
          LPTR((char*)Ks + (size_t)cbase * 16), 16, 0, 0);
      __builtin_amdgcn_global_load_lds(
          GPTR(vbase + (size_t)r * KVL + t0 + kc * 8),
          LPTR((char*)Vs + (size_t)cbase * 16), 16, 0, 0);
    }
    __syncthreads();

    // S^T = K Q^T: C-layout row = key = quad*4+r, col = q = l15
#pragma unroll
    for (int nt = 0; nt < 4; ++nt) {
      const int krow = nt * 16 + l15;
      const bf16x8 aK0 = *(const bf16x8*)&Ks[krow * 64 + ((quad ^ sw) * 8)];
      const bf16x8 aK1 = *(const bf16x8*)&Ks[krow * 64 + (((4 + quad) ^ sw) * 8)];
      f32x4 cc = {};
      cc = __builtin_amdgcn_mfma_f32_16x16x32_bf16(aK0, bQ0, cc, 0, 0, 0);
      cc = __builtin_amdgcn_mfma_f32_16x16x32_bf16(aK1, bQ1, cc, 0, 0, 0);
      const float p0 = __expf(cc[0]);
      const float p1 = __expf(cc[1]);
      const float p2 = __expf(cc[2]);
      const float p3 = __expf(cc[3]);
      l_lane += (p0 + p1) + (p2 + p3);
      uint2 pk;
      pk.x = (unsigned)f2bf(p0) | ((unsigned)f2bf(p1) << 16);
      pk.y = (unsigned)f2bf(p2) | ((unsigned)f2bf(p3) << 16);
      *(uint2*)&Ps[wid][l15][nt * 16 + quad * 4] = pk;   // keys contiguous
    }
    asm volatile("s_waitcnt lgkmcnt(0)" ::: "memory");   // wave-private Ps ready

    // O^T += Vt * P^T
#pragma unroll
    for (int kt = 0; kt < 2; ++kt) {
      const bf16x8 bP = *(const bf16x8*)&Ps[wid][l15][kt * 32 + quad * 8];
#pragma unroll
      for (int ot = 0; ot < 4; ++ot) {
        const int vrow = ot * 16 + l15;
        const bf16x8 aV = *(const bf16x8*)&Vs[vrow * 64 + (((kt * 4 + quad) ^ sw) * 8)];
        O[ot] = __builtin_amdgcn_mfma_f32_16x16x32_bf16(aV, bP, O[ot], 0, 0, 0);
      }
    }
  }

  // epilogue: unnormalized partials
  l_lane += __shfl_xor(l_lane, 16, 64);
  l_lane += __shfl_xor(l_lane, 32, 64);
  const int sbh = (sp * Bc + b) * NH + h;
  if (quad == 0) lpart[(size_t)sbh * Nn + q0 + l15] = l_lane;
  float* ap = Apart + ((size_t)sbh * 64) * Nn + q0 + l15;
#pragma unroll
  for (int ot = 0; ot < 4; ++ot)
#pragma unroll
    for (int r = 0; r < 4; ++r)
      ap[(size_t)(ot * 16 + quad * 4 + r) * Nn] = O[ot][r];
}

// ---------------- attention merge: combine splits, normalize, transpose -------
__global__ __launch_bounds__(256) void k_attn_merge(const float* __restrict__ Apart,
                                                    const float* __restrict__ lpart,
                                                    u16* __restrict__ attnout) {
  __shared__ float T[64][65];
  __shared__ float il[64];
  const int qt = blockIdx.x & 31;
  const int bh = blockIdx.x >> 5;
  const int b = bh / NH, h = bh % NH;
  const int q0 = qt * 64;
  const int bh0 = b * NH + h;
  const int bh1 = (Bc + b) * NH + h;
  if (threadIdx.x < 64) {
    const int q = threadIdx.x;
    il[q] = 1.0f / (lpart[(size_t)bh0 * Nn + q0 + q] + lpart[(size_t)bh1 * Nn + q0 + q]);
  }
  const float* a0 = Apart + ((size_t)bh0 * 64) * Nn + q0;
  const float* a1 = Apart + ((size_t)bh1 * 64) * Nn + q0;
#pragma unroll
  for (int p = 0; p < 16; ++p) {
    const int idx = p * 256 + threadIdx.x;
    const int d = idx >> 6, q = idx & 63;
    T[q][d] = a0[(size_t)d * Nn + q] + a1[(size_t)d * Nn + q];
  }
  __syncthreads();
#pragma unroll
  for (int p = 0; p < 16; ++p) {
    const int idx = p * 256 + threadIdx.x;
    const int q = idx >> 6, d = idx & 63;
    attnout[((size_t)(b * Nn + q0 + q)) * DM + h * 64 + d] = f2bf(T[q][d] * il[q]);
  }
}

// ---------------- fused GLU + depthwise conv + BN partial stats ----------------
__global__ __launch_bounds__(256) void k_dwconv2(const u16* __restrict__ pw1,
                                                 const float* __restrict__ w,
                                                 const float* __restrict__ bsd,
                                                 float* __restrict__ out,
                                                 float* __restrict__ stats) {
  __shared__ float S[94][68];
  __shared__ float Wl[31][64];
  const int cb = blockIdx.x * 64;
  const int n0 = blockIdx.y * 64;
  const int b  = blockIdx.z;
  for (int idx = threadIdx.x; idx < 94 * 16; idx += 256) {
    const int r = idx >> 4, cg = (idx & 15) * 4;
    const int n = n0 - 15 + r;
    float4 v = make_float4(0.f, 0.f, 0.f, 0.f);
    if (n >= 0 && n < Nn) {
      const u16* p = pw1 + ((size_t)(b * Nn + n)) * (2 * DM) + cb + cg;
      u16x4 av = *(const u16x4*)(p);
      u16x4 gv = *(const u16x4*)(p + DM);
      v.x = bf2f(av[0]) * sigmoidf_(bf2f(gv[0]));
      v.y = bf2f(av[1]) * sigmoidf_(bf2f(gv[1]));
      v.z = bf2f(av[2]) * sigmoidf_(bf2f(gv[2]));
      v.w = bf2f(av[3]) * sigmoidf_(bf2f(gv[3]));
    }
    *(float4*)&S[r][cg] = v;
  }
  for (int idx = threadIdx.x; idx < 31 * 64; idx += 256) {
    const int c = idx & 63, tap = idx >> 6;
    Wl[tap][c] = w[(size_t)(cb + c) * 31 + tap];
  }
  __syncthreads();

  const int cg  = (threadIdx.x & 15) * 4;
  const int nl0 = threadIdx.x >> 4;
  const float4 b4 = *(const float4*)(bsd + cb + cg);
  float sum[4] = {0.f, 0.f, 0.f, 0.f};
  float sq[4]  = {0.f, 0.f, 0.f, 0.f};
#pragma unroll
  for (int p = 0; p < 4; ++p) {
    const int nl = p * 16 + nl0;
    float a0 = b4.x, a1 = b4.y, a2 = b4.z, a3 = b4.w;
#pragma unroll
    for (int t = 0; t < 31; ++t) {
      const float4 sv = *(const float4*)&S[nl + t][cg];
      const float4 wv = *(const float4*)&Wl[t][cg & 63];
      a0 = fmaf(sv.x, wv.x, a0); a1 = fmaf(sv.y, wv.y, a1);
      a2 = fmaf(sv.z, wv.z, a2); a3 = fmaf(sv.w, wv.w, a3);
    }
    *(float4*)(out + ((size_t)(b * Nn + n0 + nl)) * DM + cb + cg) =
        make_float4(a0, a1, a2, a3);
    sum[0] += a0; sum[1] += a1; sum[2] += a2; sum[3] += a3;
    sq[0] = fmaf(a0, a0, sq[0]); sq[1] = fmaf(a1, a1, sq[1]);
    sq[2] = fmaf(a2, a2, sq[2]); sq[3] = fmaf(a3, a3, sq[3]);
  }
  __syncthreads();
  *(float4*)&S[nl0][cg]      = make_float4(sum[0], sum[1], sum[2], sum[3]);
  *(float4*)&S[16 + nl0][cg] = make_float4(sq[0], sq[1], sq[2], sq[3]);
  __syncthreads();
  if (threadIdx.x < 64) {
    const int c = threadIdx.x;
    float s = 0.f, q = 0.f;
#pragma unroll
    for (int i = 0; i < 16; ++i) { s += S[i][c]; q += S[16 + i][c]; }
    atomicAdd(&stats[cb + c], s);
    atomicAdd(&stats[DM + cb + c], q);
  }
}

__global__ __launch_bounds__(256) void k_zero(float* __restrict__ p, int n) {
  const int i = blockIdx.x * 256 + threadIdx.x;
  if (i < n) p[i] = 0.f;
}

__global__ __launch_bounds__(256) void k_bn_apply(const float* __restrict__ x,
                                                  const float* __restrict__ stats,
                                                  const float* __restrict__ g,
                                                  const float* __restrict__ bb,
                                                  u16* __restrict__ out) {
  const int idx = blockIdx.x * 256 + threadIdx.x;
  const int c = idx % DM;
  const float mean = stats[c] * (1.0f / (float)RR);
  const float var = stats[DM + c] * (1.0f / (float)RR) - mean * mean;
  float y = (x[idx] - mean) * rsqrtf(var + EPSF) * g[c] + bb[c];
  out[idx] = f2bf(y * sigmoidf_(y));
}

// ---------------- launch ----------------
extern "C" void kernel_launch(void* const* d_in, const int* in_sizes, int n_in,
                              void* d_out, int out_size, void* d_ws, size_t ws_size,
                              hipStream_t stream) {
  const float* x       = (const float*)d_in[0];
  const float* cached  = (const float*)d_in[4];
  const float* ff1_nw  = (const float*)d_in[5];
  const float* ff1_w1  = (const float*)d_in[6];
  const float* ff1_b1  = (const float*)d_in[7];
  const float* ff1_w2  = (const float*)d_in[8];
  const float* ff1_b2  = (const float*)d_in[9];
  const float* attn_nw = (const float*)d_in[10];
  const float* qkv_w   = (const float*)d_in[11];
  const float* out_w   = (const float*)d_in[12];
  const float* q_nw    = (const float*)d_in[13];
  const float* k_nw    = (const float*)d_in[14];
  const float* conv_nw = (const float*)d_in[15];
  const float* pw1_w   = (const float*)d_in[16];
  const float* pw1_b   = (const float*)d_in[17];
  const float* dw_w    = (const float*)d_in[18];
  const float* dw_b    = (const float*)d_in[19];
  const float* bn_g    = (const float*)d_in[20];
  const float* bn_b    = (const float*)d_in[21];
  const float* pw2_w   = (const float*)d_in[22];
  const float* pw2_b   = (const float*)d_in[23];
  const float* ff2_nw  = (const float*)d_in[24];
  const float* ff2_w1  = (const float*)d_in[25];
  const float* ff2_b1  = (const float*)d_in[26];
  const float* ff2_w2  = (const float*)d_in[27];
  const float* ff2_b2  = (const float*)d_in[28];
  const float* out_nw  = (const float*)d_in[29];

  float* out_x  = (float*)d_out;
  float* out_kv = out_x + (size_t)RR * DM;

  // ---- workspace layout (~143.6 MB) ----
  u16* wt_ff1w1 = (u16*)d_ws;                          // 3072 x 768
  u16* wt_ff1w2 = wt_ff1w1 + (size_t)3072 * 768;       // 768 x 3072
  u16* wt_qkv   = wt_ff1w2 + (size_t)768 * 3072;       // 2304 x 768
  u16* wt_out   = wt_qkv   + (size_t)2304 * 768;       // 768 x 768
  u16* wt_pw1   = wt_out   + (size_t)768 * 768;        // 1536 x 768
  u16* wt_pw2   = wt_pw1   + (size_t)1536 * 768;       // 768 x 768
  u16* wt_ff2w1 = wt_pw2   + (size_t)768 * 768;        // 3072 x 768
  u16* wt_ff2w2 = wt_ff2w1 + (size_t)3072 * 768;       // 768 x 3072
  u16* abuf     = wt_ff2w2 + (size_t)768 * 3072;       // RR x 768 bf16
  u16* hbuf     = abuf + (size_t)RR * DM;              // RR x 3072 bf16
  float* xA     = (float*)(hbuf + (size_t)RR * FFD);   // RR x 768 f32
  float* xB     = xA + (size_t)RR * DM;                // RR x 768 f32
  float* qkvbuf = xB + (size_t)RR * DM;                // RR x 2304 f32
  u16* qbf      = (u16*)(qkvbuf + (size_t)RR * 3 * DM);
  u16* krotbf   = qbf + (size_t)RR * DM;
  u16* vtbf     = krotbf + (size_t)Bc * KVL * DM;
  float* bn_stats = (float*)(vtbf + (size_t)Bc * KVL * DM);
  // aliases (disjoint lifetimes):
  float* Apart  = (float*)hbuf;                        // 2*2*12*64*2048 f32 = 25.2MB
  u16* attnout  = (u16*)qkvbuf;                        // RR x 768 bf16
  float* lpart  = qkvbuf + (size_t)RR * DM;            // 98304 f32
  float* dwout  = qkvbuf;                              // RR x 768 f32 (conv phase)
  u16* bnout    = (u16*)(qkvbuf + (size_t)RR * DM);    // RR x 768 bf16 (conv phase)

  const dim3 blk(256);
  // ---- weight prep ----
  k_wt<<<dim3(48, 12), blk, 0, stream>>>(ff1_w1, wt_ff1w1, DM, FFD);
  k_wt<<<dim3(12, 48), blk, 0, stream>>>(ff1_w2, wt_ff1w2, FFD, DM);
  k_wt<<<dim3(36, 12), blk, 0, stream>>>(qkv_w, wt_qkv, DM, 3 * DM);
  k_wt<<<dim3(12, 12), blk, 0, stream>>>(out_w, wt_out, DM, DM);
  k_wt<<<dim3(24, 12), blk, 0, stream>>>(pw1_w, wt_pw1, DM, 2 * DM);
  k_wt<<<dim3(12, 12), blk, 0, stream>>>(pw2_w, wt_pw2, DM, DM);
  k_wt<<<dim3(48, 12), blk, 0, stream>>>(ff2_w1, wt_ff2w1, DM, FFD);
  k_wt<<<dim3(12, 48), blk, 0, stream>>>(ff2_w2, wt_ff2w2, FFD, DM);

  // ---- FF1 ----
  k_rmsnorm2<true><<<RR, blk, 0, stream>>>(x, ff1_nw, abuf, DM);
  k_gemm_mfma<128, 1, true><<<dim3(FFD / 128, RR / 128), blk, 0, stream>>>(
      abuf, wt_ff1w1, ff1_b1, nullptr, hbuf, DM, FFD);
  k_gemm_mfma<64, 2, false><<<dim3(DM / 64, RR / 128), blk, 0, stream>>>(
      hbuf, wt_ff1w2, ff1_b2, x, xA, FFD, DM);
  // ---- Attention ----
  k_rmsnorm2<true><<<RR, blk, 0, stream>>>(xA, attn_nw, abuf, DM);
  k_gemm_mfma<128, 0, false><<<dim3(3 * DM / 128, RR / 128), blk, 0, stream>>>(
      abuf, wt_qkv, nullptr, nullptr, qkvbuf, DM, 3 * DM);
  k_qkv_post<<<RR, 768, 0, stream>>>(qkvbuf, q_nw, k_nw, qbf, krotbf, out_kv);
  k_cache_prep<<<Bc * CACHE, 768, 0, stream>>>(cached, out_kv, krotbf);
  k_vt<<<Bc * NH * (KVL / 64), blk, 0, stream>>>(out_kv, vtbf);
  k_attn2<<<Bc * NH * (Nn / 64) * 2, blk, 0, stream>>>(qbf, krotbf, vtbf, Apart, lpart);
  k_attn_merge<<<Bc * NH * (Nn / 64), blk, 0, stream>>>(Apart, lpart, attnout);
  k_gemm_mfma<64, 3, false><<<dim3(DM / 64, RR / 128), blk, 0, stream>>>(
      attnout, wt_out, nullptr, xA, xB, DM, DM);
  // ---- Conv module ----
  k_rmsnorm2<true><<<RR, blk, 0, stream>>>(xB, conv_nw, abuf, DM);
  k_gemm_mfma<128, 0, true><<<dim3(2 * DM / 128, RR / 128), blk, 0, stream>>>(
      abuf, wt_pw1, pw1_b, nullptr, hbuf, DM, 2 * DM);
  k_zero<<<6, blk, 0, stream>>>(bn_stats, 2 * DM);
  k_dwconv2<<<dim3(DM / 64, Nn / 64, Bc), blk, 0, stream>>>(hbuf, dw_w, dw_b,
                                                            dwout, bn_stats);
  k_bn_apply<<<RR * DM / 256, blk, 0, stream>>>(dwout, bn_stats, bn_g, bn_b, bnout);
  k_gemm_mfma<64, 0, false><<<dim3(DM / 64, RR / 128), blk, 0, stream>>>(
      bnout, wt_pw2, pw2_b, nullptr, xA, DM, DM);
  // ---- FF2 ----
  k_rmsnorm2<true><<<RR, blk, 0, stream>>>(xA, ff2_nw, abuf, DM);
  k_gemm_mfma<128, 1, true><<<dim3(FFD / 128, RR / 128), blk, 0, stream>>>(
      abuf, wt_ff2w1, ff2_b1, nullptr, hbuf, DM, FFD);
  k_gemm_mfma<64, 2, false><<<dim3(DM / 64, RR / 128), blk, 0, stream>>>(
      hbuf, wt_ff2w2, ff2_b2, xA, xB, FFD, DM);
  // ---- final norm ----
  k_rmsnorm2<false><<<RR, blk, 0, stream>>>(xB, out_nw, out_x, DM);
}